// Round 10
// baseline (443.894 us; speedup 1.0000x reference)
//
#include <hip/hip_runtime.h>
#include <hip/hip_bf16.h>

#define BT 65536
#define DD 512
#define HH 512
#define NE 32
#define CAP 5120
#define BM 128
#define NRB 40   /* CAP/BM */

typedef float  f32x4  __attribute__((ext_vector_type(4)));
typedef short  bf16x8 __attribute__((ext_vector_type(8)));

__device__ __forceinline__ unsigned short f2bf(float f){
    unsigned int u = __builtin_bit_cast(unsigned int, f);
    unsigned int r = (u + 0x7fffu + ((u >> 16) & 1u)) >> 16;
    return (unsigned short)r;
}
__device__ __forceinline__ float bf2f(unsigned short h){
    unsigned int u = ((unsigned int)h) << 16;
    return __builtin_bit_cast(float, u);
}

// ---------------- weight convert to MFMA-fragment-tiled bf16 ----------------
// W[e][k][n] fp32 -> Wf[e][nt(32)][kc(16)][lane(64)][8] bf16: for fragment (nt,kc)
// lane holds W[k = kc*32 + (lane>>4)*8 + j][n = nt*16 + (lane&15)].
__global__ __launch_bounds__(256) void k_wconv(
    const float* __restrict__ W1, const float* __restrict__ W2,
    unsigned short* __restrict__ W1f, unsigned short* __restrict__ W2f)
{
    int b = blockIdx.x;                    // 512 blocks
    int w = b >> 8;                        // 0: W1, 1: W2
    int e = (b >> 3) & 31;
    int kq = b & 7;                        // k-range [kq*64, kq*64+64)
    const float* src = (w ? W2 : W1) + ((size_t)e << 18);
    unsigned short* dst = (w ? W2f : W1f) + ((size_t)e << 18);
    int t = threadIdx.x;
    #pragma unroll 1
    for (int kg = 0; kg < 8; kg++){
        int k0 = kq*64 + kg*8;
        #pragma unroll
        for (int ng = 0; ng < 2; ng++){
            int n = ng*256 + t;
            unsigned short v[8];
            #pragma unroll
            for (int j = 0; j < 8; j++)
                v[j] = f2bf(src[(size_t)(k0 + j)*512 + n]);
            int nt = n >> 4, kc = k0 >> 5, ln = ((k0 >> 3) & 3)*16 + (n & 15);
            *(bf16x8*)(dst + (((size_t)(nt*16 + kc)*64 + ln) << 3)) = *(bf16x8*)v;
        }
    }
}

// ---------------- gating: wave=dim-quarter, lane=token; 1024 blocks; LDS reduce ----------------
__global__ __launch_bounds__(256) void k_gate(
    const float* __restrict__ x, const float* __restrict__ Wg,
    int* __restrict__ counts, int* __restrict__ gsl, float* __restrict__ wts,
    unsigned char* __restrict__ flags)
{
    __shared__ float pacc[4][64][36];   // [quarter][token][expert], padded
    __shared__ int lcnt[NE], lbase[NE];

    int tid = threadIdx.x;
    int l   = tid & 63;                                    // local token
    int q   = __builtin_amdgcn_readfirstlane(tid >> 6);    // dim-quarter (wave-uniform)

    const float* xq = x + ((size_t)(blockIdx.x*64 + l))*DD + q*128;

    float acc[NE];
    #pragma unroll
    for (int n = 0; n < NE; n++) acc[n] = 0.f;

    float4 xa = *(const float4*)(xq);
    float4 xb = *(const float4*)(xq + 4);
    #pragma unroll 1
    for (int d = 0; d < 128; d += 8){
        int dn = (d + 8 < 128) ? (d + 8) : 0;
        float4 na = *(const float4*)(xq + dn);
        float4 nb = *(const float4*)(xq + dn + 4);
        #pragma unroll
        for (int j = 0; j < 8; j++){
            float xv = (j < 4) ? ((j==0)?xa.x:(j==1)?xa.y:(j==2)?xa.z:xa.w)
                               : ((j==4)?xb.x:(j==5)?xb.y:(j==6)?xb.z:xb.w);
            const float4* wr = (const float4*)(Wg + (size_t)(q*128 + d + j)*NE); // uniform -> s_load
            #pragma unroll
            for (int p = 0; p < 8; p++){
                float4 w4 = wr[p];
                acc[p*4+0] = fmaf(xv, w4.x, acc[p*4+0]);
                acc[p*4+1] = fmaf(xv, w4.y, acc[p*4+1]);
                acc[p*4+2] = fmaf(xv, w4.z, acc[p*4+2]);
                acc[p*4+3] = fmaf(xv, w4.w, acc[p*4+3]);
            }
        }
        xa = na; xb = nb;
    }

    #pragma unroll
    for (int n4 = 0; n4 < 8; n4++){
        float4 v; v.x = acc[n4*4]; v.y = acc[n4*4+1]; v.z = acc[n4*4+2]; v.w = acc[n4*4+3];
        *(float4*)&pacc[q][l][n4*4] = v;
    }
    if (tid < NE) lcnt[tid] = 0;
    __syncthreads();

    bool owner = (q == (l & 3));
    int tok = blockIdx.x*64 + l;
    int i1 = 0, i2 = 0, g1 = 0, g2 = 0;
    float w1 = 0.f, w2 = 0.f;

    if (owner){
        #pragma unroll
        for (int n4 = 0; n4 < 8; n4++){
            float4 p0 = *(float4*)&pacc[0][l][n4*4];
            float4 p1 = *(float4*)&pacc[1][l][n4*4];
            float4 p2 = *(float4*)&pacc[2][l][n4*4];
            float4 p3 = *(float4*)&pacc[3][l][n4*4];
            acc[n4*4+0] = (p0.x + p1.x) + (p2.x + p3.x);
            acc[n4*4+1] = (p0.y + p1.y) + (p2.y + p3.y);
            acc[n4*4+2] = (p0.z + p1.z) + (p2.z + p3.z);
            acc[n4*4+3] = (p0.w + p1.w) + (p2.w + p3.w);
        }

        float v1 = -1e30f; i1 = -1;
        #pragma unroll
        for (int n = 0; n < NE; n++) if (acc[n] > v1){ v1 = acc[n]; i1 = n; }
        float v2 = -1e30f; i2 = -1;
        #pragma unroll
        for (int n = 0; n < NE; n++) if (n != i1 && acc[n] > v2){ v2 = acc[n]; i2 = n; }
        float v3 = -1e30f;
        #pragma unroll
        for (int n = 0; n < NE; n++) if (n != i1 && n != i2 && acc[n] > v3) v3 = acc[n];

        if (v2 - v3 >= 1e-4f){
            double ex  = exp((double)v2 - (double)v1);
            double inv = 1.0 / (1.0 + ex);
            w1 = (float)inv; w2 = (float)(ex * inv);
        } else {
            // rare: resolve {top2} among near-tie candidates in fp64
            const float* xr = x + (size_t)tok * DD;
            float thresh = v2 - 1e-3f;
            unsigned cmask = 0u;
            #pragma unroll
            for (int n = 0; n < NE; n++) cmask |= (acc[n] >= thresh) ? (1u << n) : 0u;
            double dv1 = -1.0e300, dv2 = -1.0e300; int di1 = -1, di2 = -1;
            #pragma unroll 1
            for (int n = 0; n < NE; n++){
                if (!((cmask >> n) & 1u)) continue;
                double s0 = 0.0, s1 = 0.0, s2 = 0.0, s3 = 0.0;
                #pragma unroll 4
                for (int d = 0; d < DD; d += 4){
                    s0 = fma((double)xr[d+0], (double)Wg[(size_t)(d+0)*NE + n], s0);
                    s1 = fma((double)xr[d+1], (double)Wg[(size_t)(d+1)*NE + n], s1);
                    s2 = fma((double)xr[d+2], (double)Wg[(size_t)(d+2)*NE + n], s2);
                    s3 = fma((double)xr[d+3], (double)Wg[(size_t)(d+3)*NE + n], s3);
                }
                double s = (s0 + s1) + (s2 + s3);
                if (s > dv1){ dv2 = dv1; di2 = di1; dv1 = s; di1 = n; }
                else if (s > dv2){ dv2 = s; di2 = n; }
            }
            i1 = di1; i2 = di2;
            double ex  = exp(dv2 - dv1);
            double inv = 1.0 / (1.0 + ex);
            w1 = (float)inv; w2 = (float)(ex * inv);
        }
        g1 = atomicAdd(&lcnt[i1], 1);
        g2 = atomicAdd(&lcnt[i2], 1);
    }
    __syncthreads();
    if (tid < NE && lcnt[tid] > 0) lbase[tid] = atomicAdd(&counts[tid], lcnt[tid]);
    __syncthreads();
    if (owner){
        g1 += lbase[i1];
        g2 += lbase[i2];
        bool k1 = g1 < CAP, k2 = g2 < CAP;
        if (k1){ gsl[i1*CAP + g1] = tok;               wts[i1*CAP + g1] = w1; }
        if (k2){ gsl[i2*CAP + g2] = tok | (1 << 20);   wts[i2*CAP + g2] = w2; }
        flags[tok] = (unsigned char)((k1 ? 1 : 0) | (k2 ? 2 : 0));
    }
}

// ---------------- fused expert FFN v6: BM=128, pipelined dim-half staging ----------------
// LDS: during layer1, X stored as [half][tok(128)][256 dims bf16 = 512B], swizzled.
// After layer1, same 128KB holds h as [tok(128)][512 bf16 = 1KB], swizzled.
__global__ __launch_bounds__(512, 2) void k_ffn(
    const float* __restrict__ x,
    const unsigned short* __restrict__ W1f,
    const unsigned short* __restrict__ W2f,
    const float* __restrict__ b1, const float* __restrict__ b2,
    const int* __restrict__ counts,
    const int* __restrict__ gsl, const float* __restrict__ wts,
    float* __restrict__ y, unsigned short* __restrict__ y2h)
{
    __shared__ unsigned char AH[131072];

    // XCD swizzle: all 40 blocks of expert e land on XCD e&7
    int p  = blockIdx.x;
    int s  = p >> 3;
    int e  = ((s / NRB) << 3) | (p & 7);
    int rb = s % NRB;

    int cnt = counts[e]; if (cnt > CAP) cnt = CAP;
    int r0 = rb * BM;
    if (r0 >= cnt) return;

    int tid  = threadIdx.x;
    int lane = tid & 63;
    int wv   = tid >> 6;      // 8 waves: wave owns hidden/output cols [wv*64, wv*64+64)
    int lg   = lane >> 4;
    int ll   = lane & 15;

    // staging role: thread covers row srow (0..127), dim-segment sseg (64 dims of the half)
    int srow = tid >> 2, sseg = tid & 3;
    int sgr  = r0 + srow;
    bool svalid = sgr < cnt;
    int stk = svalid ? (gsl[e*CAP + sgr] & 0xFFFFF) : 0;
    const float* sx = x + (size_t)stk*DD + sseg*64;
    char* srowb = (char*)AH + srow*512;
    int ssw = (srow & 7) << 4;

    // ---- stage half0 (dims 0..255) ----
    #pragma unroll 4
    for (int i = 0; i < 8; i++){
        float4 v0, v1;
        if (svalid){ v0 = *(const float4*)(sx + i*8); v1 = *(const float4*)(sx + i*8 + 4); }
        else { v0.x=v0.y=v0.z=v0.w=0.f; v1=v0; }
        uint2 pk;
        pk.x = (unsigned)f2bf(v0.x) | ((unsigned)f2bf(v0.y) << 16);
        pk.y = (unsigned)f2bf(v0.z) | ((unsigned)f2bf(v0.w) << 16);
        uint2 pk2;
        pk2.x = (unsigned)f2bf(v1.x) | ((unsigned)f2bf(v1.y) << 16);
        pk2.y = (unsigned)f2bf(v1.z) | ((unsigned)f2bf(v1.w) << 16);
        int dl = sseg*64 + i*8;
        int cl = dl >> 3;
        *(uint2*)(srowb + ((cl ^ (srow & 7)) << 4))     = pk;
        *(uint2*)(srowb + ((cl ^ (srow & 7)) << 4) + 8) = pk2;
    }
    __syncthreads();

    f32x4 acc[4][8];          // layer1: [ntile][toktile]; layer2: [dtile][toktile]
    #pragma unroll
    for (int a2 = 0; a2 < 4; a2++)
        #pragma unroll
        for (int tt = 0; tt < 8; tt++)
            acc[a2][tt] = (f32x4)0.f;

    // ---- layer 1 (swapped): acc[a][tt] += W1^T-frag(a,c) x X-frag(tt,c) ----
    // X frag read: byte-chunk cc = c*4+lg; half hf = cc>>5, cl = cc&31.
    {
        const unsigned short* Wa = W1f + ((size_t)e << 18) + (size_t)wv*32768;
        bf16x8 f0[4], f1[4];
        #pragma unroll
        for (int a2 = 0; a2 < 4; a2++)
            f0[a2] = *(const bf16x8*)(Wa + a2*8192 + lane*8);
        #pragma unroll 1
        for (int c = 0; c < 16; c += 2){
            #pragma unroll
            for (int a2 = 0; a2 < 4; a2++)
                f1[a2] = *(const bf16x8*)(Wa + a2*8192 + (c+1)*512 + lane*8);
            if (c < 8){
                // stage half1: 4 float4 per c-pair (16 total over c=0,2,4,6)
                #pragma unroll
                for (int u = 0; u < 4; u++){
                    int i = (c >> 1)*4 + u;            // 0..15
                    float4 v;
                    if (svalid) v = *(const float4*)(sx + 256 + i*4);
                    else { v.x=v.y=v.z=v.w=0.f; }
                    uint2 pk;
                    pk.x = (unsigned)f2bf(v.x) | ((unsigned)f2bf(v.y) << 16);
                    pk.y = (unsigned)f2bf(v.z) | ((unsigned)f2bf(v.w) << 16);
                    int dl = sseg*64 + i*4;
                    int cl = dl >> 3;
                    *(uint2*)(srowb + 65536 + ((cl ^ (srow & 7)) << 4) + (dl & 7)*2) = pk;
                }
            }
            // compute chunk c (f0)
            #pragma unroll
            for (int tp = 0; tp < 4; tp++){
                int cc = c*4 + lg, hf = cc >> 5, cl = cc & 31;
                int t0 = tp*32 + ll, t1 = tp*32 + 16 + ll;
                bf16x8 bx0 = *(const bf16x8*)((char*)AH + hf*65536 + t0*512 + ((cl ^ (t0 & 7)) << 4));
                bf16x8 bx1 = *(const bf16x8*)((char*)AH + hf*65536 + t1*512 + ((cl ^ (t1 & 7)) << 4));
                #pragma unroll
                for (int a2 = 0; a2 < 4; a2++){
                    acc[a2][tp*2]   = __builtin_amdgcn_mfma_f32_16x16x32_bf16(f0[a2], bx0, acc[a2][tp*2],   0, 0, 0);
                    acc[a2][tp*2+1] = __builtin_amdgcn_mfma_f32_16x16x32_bf16(f0[a2], bx1, acc[a2][tp*2+1], 0, 0, 0);
                }
            }
            if (c + 2 < 16){
                #pragma unroll
                for (int a2 = 0; a2 < 4; a2++)
                    f0[a2] = *(const bf16x8*)(Wa + a2*8192 + (c+2)*512 + lane*8);
            }
            // compute chunk c+1 (f1)
            #pragma unroll
            for (int tp = 0; tp < 4; tp++){
                int cc = (c+1)*4 + lg, hf = cc >> 5, cl = cc & 31;
                int t0 = tp*32 + ll, t1 = tp*32 + 16 + ll;
                bf16x8 bx0 = *(const bf16x8*)((char*)AH + hf*65536 + t0*512 + ((cl ^ (t0 & 7)) << 4));
                bf16x8 bx1 = *(const bf16x8*)((char*)AH + hf*65536 + t1*512 + ((cl ^ (t1 & 7)) << 4));
                #pragma unroll
                for (int a2 = 0; a2 < 4; a2++){
                    acc[a2][tp*2]   = __builtin_amdgcn_mfma_f32_16x16x32_bf16(f1[a2], bx0, acc[a2][tp*2],   0, 0, 0);
                    acc[a2][tp*2+1] = __builtin_amdgcn_mfma_f32_16x16x32_bf16(f1[a2], bx1, acc[a2][tp*2+1], 0, 0, 0);
                }
            }
            if (c == 6) __syncthreads();   // half1 staged before c=8 reads it
        }
    }
    __syncthreads();   // all X reads done; AH can be overwritten by h

    // ---- h = relu(acc + b1) -> AH as h[tok][n] (1KB rows), packed 8B writes ----
    #pragma unroll
    for (int a2 = 0; a2 < 4; a2++){
        int n0 = wv*64 + a2*16 + lg*4;
        float4 bv = *(const float4*)(b1 + e*HH + n0);
        #pragma unroll
        for (int tt = 0; tt < 8; tt++){
            int tok = tt*16 + ll;
            float h0 = acc[a2][tt][0] + bv.x; h0 = h0 > 0.f ? h0 : 0.f;
            float h1 = acc[a2][tt][1] + bv.y; h1 = h1 > 0.f ? h1 : 0.f;
            float h2 = acc[a2][tt][2] + bv.z; h2 = h2 > 0.f ? h2 : 0.f;
            float h3 = acc[a2][tt][3] + bv.w; h3 = h3 > 0.f ? h3 : 0.f;
            uint2 pk;
            pk.x = (unsigned)f2bf(h0) | ((unsigned)f2bf(h1) << 16);
            pk.y = (unsigned)f2bf(h2) | ((unsigned)f2bf(h3) << 16);
            int bofs = (n0*2) ^ ((tok & 7) << 4);
            *(uint2*)((char*)AH + tok*1024 + bofs) = pk;
            acc[a2][tt] = (f32x4)0.f;
        }
    }
    __syncthreads();

    // ---- layer 2: acc[b][tt] += h-frag(tt,kc) @ W2-frag(b,kc) ----
    {
        const unsigned short* Wb = W2f + ((size_t)e << 18) + (size_t)wv*32768;
        bf16x8 f0[4], f1[4];
        #pragma unroll
        for (int b_ = 0; b_ < 4; b_++)
            f0[b_] = *(const bf16x8*)(Wb + b_*8192 + lane*8);
        #pragma unroll 1
        for (int kc = 0; kc < 16; kc += 2){
            #pragma unroll
            for (int b_ = 0; b_ < 4; b_++)
                f1[b_] = *(const bf16x8*)(Wb + b_*8192 + (kc+1)*512 + lane*8);
            #pragma unroll
            for (int tp = 0; tp < 4; tp++){
                int bo = (kc*4 + lg) << 4;
                int t0 = tp*32 + ll, t1 = tp*32 + 16 + ll;
                bf16x8 a0 = *(const bf16x8*)((char*)AH + t0*1024 + (bo ^ ((t0 & 7) << 4)));
                bf16x8 a1 = *(const bf16x8*)((char*)AH + t1*1024 + (bo ^ ((t1 & 7) << 4)));
                #pragma unroll
                for (int b_ = 0; b_ < 4; b_++){
                    acc[b_][tp*2]   = __builtin_amdgcn_mfma_f32_16x16x32_bf16(a0, f0[b_], acc[b_][tp*2],   0, 0, 0);
                    acc[b_][tp*2+1] = __builtin_amdgcn_mfma_f32_16x16x32_bf16(a1, f0[b_], acc[b_][tp*2+1], 0, 0, 0);
                }
            }
            if (kc + 2 < 16){
                #pragma unroll
                for (int b_ = 0; b_ < 4; b_++)
                    f0[b_] = *(const bf16x8*)(Wb + b_*8192 + (kc+2)*512 + lane*8);
            }
            #pragma unroll
            for (int tp = 0; tp < 4; tp++){
                int bo = ((kc+1)*4 + lg) << 4;
                int t0 = tp*32 + ll, t1 = tp*32 + 16 + ll;
                bf16x8 a0 = *(const bf16x8*)((char*)AH + t0*1024 + (bo ^ ((t0 & 7) << 4)));
                bf16x8 a1 = *(const bf16x8*)((char*)AH + t1*1024 + (bo ^ ((t1 & 7) << 4)));
                #pragma unroll
                for (int b_ = 0; b_ < 4; b_++){
                    acc[b_][tp*2]   = __builtin_amdgcn_mfma_f32_16x16x32_bf16(a0, f1[b_], acc[b_][tp*2],   0, 0, 0);
                    acc[b_][tp*2+1] = __builtin_amdgcn_mfma_f32_16x16x32_bf16(a1, f1[b_], acc[b_][tp*2+1], 0, 0, 0);
                }
            }
        }
    }

    // ---- epilogue: top-1 -> y (fp32, unweighted sum slot w*o), top-2 -> y2h (bf16, weighted) ----
    float bb[4];
    #pragma unroll
    for (int b_ = 0; b_ < 4; b_++)
        bb[b_] = b2[e*DD + wv*64 + b_*16 + ll];

    #pragma unroll
    for (int tt = 0; tt < 8; tt++){
        #pragma unroll
        for (int i = 0; i < 4; i++){
            int rl = tt*16 + lg*4 + i;
            int gr = r0 + rl;
            if (gr < cnt){
                int   v  = gsl[e*CAP + gr];
                int   tk = v & 0xFFFFF;
                float w  = wts[e*CAP + gr];
                if (v >> 20){
                    unsigned short* dst = y2h + (size_t)tk * DD;
                    #pragma unroll
                    for (int b_ = 0; b_ < 4; b_++){
                        int col = wv*64 + b_*16 + ll;
                        dst[col] = f2bf(w * (acc[b_][tt][i] + bb[b_]));
                    }
                } else {
                    float* dst = y + (size_t)tk * DD;
                    #pragma unroll
                    for (int b_ = 0; b_ < 4; b_++){
                        int col = wv*64 + b_*16 + ll;
                        dst[col] = w * (acc[b_][tt][i] + bb[b_]);
                    }
                }
            }
        }
    }
}

// ---------------- combine: y = [k1]y + [k2]bf16(y2), or passthrough x ----------------
__global__ __launch_bounds__(256) void k_comb(
    const float* __restrict__ x, const unsigned short* __restrict__ y2h,
    const unsigned char* __restrict__ flags, float* __restrict__ y)
{
    const float4* x4  = (const float4*)x;
    const uint2*  y24 = (const uint2*)y2h;     // 4 bf16 per float4-index
    float4* y4 = (float4*)y;
    int nthreads = gridDim.x * 256;
    int g = blockIdx.x * 256 + threadIdx.x;
    #pragma unroll 1
    for (long long idx = g; idx < (long long)BT * 128; idx += nthreads){
        int t = (int)(idx >> 7);
        int f = flags[t];
        if (f == 3){
            float4 a = y4[idx];
            uint2 p = y24[idx];
            a.x += bf2f((unsigned short)(p.x & 0xFFFF));
            a.y += bf2f((unsigned short)(p.x >> 16));
            a.z += bf2f((unsigned short)(p.y & 0xFFFF));
            a.w += bf2f((unsigned short)(p.y >> 16));
            y4[idx] = a;
        } else if (f == 2){
            uint2 p = y24[idx];
            float4 a;
            a.x = bf2f((unsigned short)(p.x & 0xFFFF));
            a.y = bf2f((unsigned short)(p.x >> 16));
            a.z = bf2f((unsigned short)(p.y & 0xFFFF));
            a.w = bf2f((unsigned short)(p.y >> 16));
            y4[idx] = a;
        } else if (f == 0){
            y4[idx] = x4[idx];
        } // f == 1: y already correct
    }
}

extern "C" void kernel_launch(void* const* d_in, const int* in_sizes, int n_in,
                              void* d_out, int out_size, void* d_ws, size_t ws_size,
                              hipStream_t stream)
{
    const float* x  = (const float*)d_in[0];
    const float* Wg = (const float*)d_in[1];
    const float* W1 = (const float*)d_in[2];
    const float* b1 = (const float*)d_in[3];
    const float* W2 = (const float*)d_in[4];
    const float* b2 = (const float*)d_in[5];
    float* y = (float*)d_out;

    char* ws = (char*)d_ws;
    unsigned short* W1f = (unsigned short*)(ws);
    unsigned short* W2f = (unsigned short*)(ws + 16777216);
    int*   counts = (int*)  (ws + 33554432);
    int*   gsl    = (int*)  (ws + 33554432 + 256);
    float* wts    = (float*)(ws + 33554432 + 256 + 655360);
    unsigned char* flags = (unsigned char*)(ws + 33554432 + 256 + 2*655360);
    unsigned short* y2h  = (unsigned short*)(ws + 35651584);   // 67 MB

    hipMemsetAsync(counts, 0, 256, stream);
    hipLaunchKernelGGL(k_wconv, dim3(512), dim3(256), 0, stream, W1, W2, W1f, W2f);
    hipLaunchKernelGGL(k_gate,  dim3(BT/64), dim3(256), 0, stream, x, Wg, counts, gsl, wts, flags);
    hipLaunchKernelGGL(k_ffn,   dim3(NE*NRB), dim3(512), 0, stream, x, W1f, W2f, b1, b2, counts, gsl, wts, y, y2h);
    hipLaunchKernelGGL(k_comb,  dim3(2048), dim3(256), 0, stream, x, y2h, flags, y);
}

// Round 11
// 421.597 us; speedup vs baseline: 1.0529x; 1.0529x over previous
//
#include <hip/hip_runtime.h>
#include <hip/hip_bf16.h>

#define BT 65536
#define DD 512
#define HH 512
#define NE 32
#define CAP 5120
#define BM 64
#define NRB 80   /* CAP/BM */

typedef float  f32x4  __attribute__((ext_vector_type(4)));
typedef short  bf16x8 __attribute__((ext_vector_type(8)));

__device__ __forceinline__ unsigned short f2bf(float f){
    unsigned int u = __builtin_bit_cast(unsigned int, f);
    unsigned int r = (u + 0x7fffu + ((u >> 16) & 1u)) >> 16;
    return (unsigned short)r;
}
__device__ __forceinline__ float bf2f(unsigned short h){
    unsigned int u = ((unsigned int)h) << 16;
    return __builtin_bit_cast(float, u);
}

// ---------------- prep: blocks [0,512) = weight fragment-tiling; [512,1536) = gating ----------------
// Wf layout: W[e][k][n] fp32 -> Wf[e][nt(32)][kc(16)][lane(64)][8] bf16; for fragment (nt,kc)
// lane holds W[k = kc*32 + (lane>>4)*8 + j][n = nt*16 + (lane&15)].
__global__ __launch_bounds__(256) void k_prep(
    const float* __restrict__ x, const float* __restrict__ Wg,
    const float* __restrict__ W1, const float* __restrict__ W2,
    unsigned short* __restrict__ W1f, unsigned short* __restrict__ W2f,
    int* __restrict__ counts, int* __restrict__ gsl, float* __restrict__ wts,
    unsigned char* __restrict__ flags, unsigned short* __restrict__ xb16)
{
    __shared__ float pacc[4][64][36];   // gate: [quarter][token][expert], padded
    __shared__ int lcnt[NE], lbase[NE];

    int tid = threadIdx.x;

    if (blockIdx.x < 512){
        // ---------------- weight convert ----------------
        int b = blockIdx.x;
        int w = b >> 8;
        int e = (b >> 3) & 31;
        int kq = b & 7;
        const float* src = (w ? W2 : W1) + ((size_t)e << 18);
        unsigned short* dst = (w ? W2f : W1f) + ((size_t)e << 18);
        #pragma unroll 1
        for (int kg = 0; kg < 8; kg++){
            int k0 = kq*64 + kg*8;
            #pragma unroll
            for (int ng = 0; ng < 2; ng++){
                int n = ng*256 + tid;
                unsigned short v[8];
                #pragma unroll
                for (int j = 0; j < 8; j++)
                    v[j] = f2bf(src[(size_t)(k0 + j)*512 + n]);
                int nt = n >> 4, kc = k0 >> 5, ln = ((k0 >> 3) & 3)*16 + (n & 15);
                *(bf16x8*)(dst + (((size_t)(nt*16 + kc)*64 + ln) << 3)) = *(bf16x8*)v;
            }
        }
        return;
    }

    // ---------------- gating: wave=dim-quarter, lane=token ----------------
    int blk = blockIdx.x - 512;
    int l   = tid & 63;
    int q   = __builtin_amdgcn_readfirstlane(tid >> 6);
    int tok = blk*64 + l;

    const float* xq = x + (size_t)tok*DD + q*128;

    float acc[NE];
    #pragma unroll
    for (int n = 0; n < NE; n++) acc[n] = 0.f;

    float4 xa = *(const float4*)(xq);
    float4 xb = *(const float4*)(xq + 4);
    #pragma unroll 1
    for (int d = 0; d < 128; d += 8){
        int dn = (d + 8 < 128) ? (d + 8) : 0;
        float4 na = *(const float4*)(xq + dn);
        float4 nb = *(const float4*)(xq + dn + 4);
        // byproduct: bf16 copy of x for the FFN's gather
        uint4 pk;
        pk.x = (unsigned)f2bf(xa.x) | ((unsigned)f2bf(xa.y) << 16);
        pk.y = (unsigned)f2bf(xa.z) | ((unsigned)f2bf(xa.w) << 16);
        pk.z = (unsigned)f2bf(xb.x) | ((unsigned)f2bf(xb.y) << 16);
        pk.w = (unsigned)f2bf(xb.z) | ((unsigned)f2bf(xb.w) << 16);
        *(uint4*)(xb16 + (size_t)tok*DD + q*128 + d) = pk;
        #pragma unroll
        for (int j = 0; j < 8; j++){
            float xv = (j < 4) ? ((j==0)?xa.x:(j==1)?xa.y:(j==2)?xa.z:xa.w)
                               : ((j==4)?xb.x:(j==5)?xb.y:(j==6)?xb.z:xb.w);
            const float4* wr = (const float4*)(Wg + (size_t)(q*128 + d + j)*NE); // uniform -> s_load
            #pragma unroll
            for (int p = 0; p < 8; p++){
                float4 w4 = wr[p];
                acc[p*4+0] = fmaf(xv, w4.x, acc[p*4+0]);
                acc[p*4+1] = fmaf(xv, w4.y, acc[p*4+1]);
                acc[p*4+2] = fmaf(xv, w4.z, acc[p*4+2]);
                acc[p*4+3] = fmaf(xv, w4.w, acc[p*4+3]);
            }
        }
        xa = na; xb = nb;
    }

    #pragma unroll
    for (int n4 = 0; n4 < 8; n4++){
        float4 v; v.x = acc[n4*4]; v.y = acc[n4*4+1]; v.z = acc[n4*4+2]; v.w = acc[n4*4+3];
        *(float4*)&pacc[q][l][n4*4] = v;
    }
    if (tid < NE) lcnt[tid] = 0;
    __syncthreads();

    bool owner = (q == (l & 3));
    int i1 = 0, i2 = 0, g1 = 0, g2 = 0;
    float w1 = 0.f, w2 = 0.f;

    if (owner){
        #pragma unroll
        for (int n4 = 0; n4 < 8; n4++){
            float4 p0 = *(float4*)&pacc[0][l][n4*4];
            float4 p1 = *(float4*)&pacc[1][l][n4*4];
            float4 p2 = *(float4*)&pacc[2][l][n4*4];
            float4 p3 = *(float4*)&pacc[3][l][n4*4];
            acc[n4*4+0] = (p0.x + p1.x) + (p2.x + p3.x);
            acc[n4*4+1] = (p0.y + p1.y) + (p2.y + p3.y);
            acc[n4*4+2] = (p0.z + p1.z) + (p2.z + p3.z);
            acc[n4*4+3] = (p0.w + p1.w) + (p2.w + p3.w);
        }

        float v1 = -1e30f; i1 = -1;
        #pragma unroll
        for (int n = 0; n < NE; n++) if (acc[n] > v1){ v1 = acc[n]; i1 = n; }
        float v2 = -1e30f; i2 = -1;
        #pragma unroll
        for (int n = 0; n < NE; n++) if (n != i1 && acc[n] > v2){ v2 = acc[n]; i2 = n; }
        float v3 = -1e30f;
        #pragma unroll
        for (int n = 0; n < NE; n++) if (n != i1 && n != i2 && acc[n] > v3) v3 = acc[n];

        if (v2 - v3 >= 1e-4f){
            double ex  = exp((double)v2 - (double)v1);
            double inv = 1.0 / (1.0 + ex);
            w1 = (float)inv; w2 = (float)(ex * inv);
        } else {
            // rare: resolve {top2} among near-tie candidates in fp64
            const float* xr = x + (size_t)tok * DD;
            float thresh = v2 - 1e-3f;
            unsigned cmask = 0u;
            #pragma unroll
            for (int n = 0; n < NE; n++) cmask |= (acc[n] >= thresh) ? (1u << n) : 0u;
            double dv1 = -1.0e300, dv2 = -1.0e300; int di1 = -1, di2 = -1;
            #pragma unroll 1
            for (int n = 0; n < NE; n++){
                if (!((cmask >> n) & 1u)) continue;
                double s0 = 0.0, s1 = 0.0, s2 = 0.0, s3 = 0.0;
                #pragma unroll 4
                for (int d = 0; d < DD; d += 4){
                    s0 = fma((double)xr[d+0], (double)Wg[(size_t)(d+0)*NE + n], s0);
                    s1 = fma((double)xr[d+1], (double)Wg[(size_t)(d+1)*NE + n], s1);
                    s2 = fma((double)xr[d+2], (double)Wg[(size_t)(d+2)*NE + n], s2);
                    s3 = fma((double)xr[d+3], (double)Wg[(size_t)(d+3)*NE + n], s3);
                }
                double s = (s0 + s1) + (s2 + s3);
                if (s > dv1){ dv2 = dv1; di2 = di1; dv1 = s; di1 = n; }
                else if (s > dv2){ dv2 = s; di2 = n; }
            }
            i1 = di1; i2 = di2;
            double ex  = exp(dv2 - dv1);
            double inv = 1.0 / (1.0 + ex);
            w1 = (float)inv; w2 = (float)(ex * inv);
        }
        g1 = atomicAdd(&lcnt[i1], 1);
        g2 = atomicAdd(&lcnt[i2], 1);
    }
    __syncthreads();
    if (tid < NE && lcnt[tid] > 0) lbase[tid] = atomicAdd(&counts[tid], lcnt[tid]);
    __syncthreads();
    if (owner){
        g1 += lbase[i1];
        g2 += lbase[i2];
        bool k1 = g1 < CAP, k2 = g2 < CAP;
        if (k1){ gsl[i1*CAP + g1] = tok;               wts[i1*CAP + g1] = w1; }
        if (k2){ gsl[i2*CAP + g2] = tok | (1 << 20);   wts[i2*CAP + g2] = w2; }
        flags[tok] = (unsigned char)((k1 ? 1 : 0) | (k2 ? 2 : 0));
    }
}

// ---------------- fused expert FFN: BM=64, bf16-x staging, split-destination epilogue ----------------
__global__ __launch_bounds__(512, 4) void k_ffn(
    const unsigned short* __restrict__ xb16,
    const unsigned short* __restrict__ W1f,
    const unsigned short* __restrict__ W2f,
    const float* __restrict__ b1, const float* __restrict__ b2,
    const int* __restrict__ counts,
    const int* __restrict__ gsl, const float* __restrict__ wts,
    float* __restrict__ y, unsigned short* __restrict__ y2h)
{
    __shared__ unsigned char AH[64 * 1024];   // [tok(64)][512 bf16], 16B-chunk XOR swizzle ((tok&7)<<4)

    int p  = blockIdx.x;
    int s  = p >> 3;
    int e  = ((s / NRB) << 3) | (p & 7);
    int rb = s % NRB;

    int cnt = counts[e]; if (cnt > CAP) cnt = CAP;
    int r0 = rb * BM;
    if (r0 >= cnt) return;

    int tid  = threadIdx.x;
    int lane = tid & 63;
    int wv   = tid >> 6;      // 8 waves: wave owns hidden/output cols [wv*64, wv*64+64)
    int lg   = lane >> 4;
    int ll   = lane & 15;

    // ---- stage X from bf16 copy (16B chunks, no conversion) ----
    {
        int row = tid >> 3, seg = tid & 7;
        int gr  = r0 + row;
        char* rowb = (char*)AH + row * 1024;
        int rsw = (row & 7) << 4;
        if (gr < cnt){
            int tk = gsl[e*CAP + gr] & 0xFFFFF;
            const uint4* src = (const uint4*)(xb16 + (size_t)tk*DD + seg*64);
            #pragma unroll
            for (int j = 0; j < 8; j++){
                uint4 v = src[j];
                int chunk = seg*8 + j;
                *(uint4*)(rowb + ((chunk << 4) ^ rsw)) = v;
            }
        } else {
            uint4 zz; zz.x = zz.y = zz.z = zz.w = 0u;
            #pragma unroll
            for (int j = 0; j < 8; j++){
                int chunk = seg*8 + j;
                *(uint4*)(rowb + ((chunk << 4) ^ rsw)) = zz;
            }
        }
    }
    __syncthreads();

    f32x4 acc[4][4];
    #pragma unroll
    for (int a2 = 0; a2 < 4; a2++)
        #pragma unroll
        for (int tt = 0; tt < 4; tt++)
            acc[a2][tt] = (f32x4)0.f;

    // ---- layer 1 (swapped): acc[a][tt] += W1^T-frag(a,c) x X-frag(tt,c) ----
    {
        const unsigned short* Wa = W1f + ((size_t)e << 18) + (size_t)wv*32768;
        bf16x8 f0[4], f1[4];
        #pragma unroll
        for (int a2 = 0; a2 < 4; a2++)
            f0[a2] = *(const bf16x8*)(Wa + a2*8192 + lane*8);
        #pragma unroll 1
        for (int c = 0; c < 16; c += 2){
            #pragma unroll
            for (int a2 = 0; a2 < 4; a2++)
                f1[a2] = *(const bf16x8*)(Wa + a2*8192 + (c+1)*512 + lane*8);
            {
                bf16x8 bx[4];
                #pragma unroll
                for (int tt = 0; tt < 4; tt++){
                    int tok = tt*16 + ll;
                    int bofs = (64*c + 16*lg) ^ ((tok & 7) << 4);
                    bx[tt] = *(const bf16x8*)((char*)AH + tok*1024 + bofs);
                }
                #pragma unroll
                for (int a2 = 0; a2 < 4; a2++)
                    #pragma unroll
                    for (int tt = 0; tt < 4; tt++)
                        acc[a2][tt] = __builtin_amdgcn_mfma_f32_16x16x32_bf16(f0[a2], bx[tt], acc[a2][tt], 0, 0, 0);
            }
            if (c + 2 < 16){
                #pragma unroll
                for (int a2 = 0; a2 < 4; a2++)
                    f0[a2] = *(const bf16x8*)(Wa + a2*8192 + (c+2)*512 + lane*8);
            }
            {
                bf16x8 bx[4];
                #pragma unroll
                for (int tt = 0; tt < 4; tt++){
                    int tok = tt*16 + ll;
                    int bofs = (64*(c+1) + 16*lg) ^ ((tok & 7) << 4);
                    bx[tt] = *(const bf16x8*)((char*)AH + tok*1024 + bofs);
                }
                #pragma unroll
                for (int a2 = 0; a2 < 4; a2++)
                    #pragma unroll
                    for (int tt = 0; tt < 4; tt++)
                        acc[a2][tt] = __builtin_amdgcn_mfma_f32_16x16x32_bf16(f1[a2], bx[tt], acc[a2][tt], 0, 0, 0);
            }
        }
    }
    __syncthreads();

    // ---- h = relu(acc + b1) -> AH as h[tok][n], packed 8B writes ----
    #pragma unroll
    for (int a2 = 0; a2 < 4; a2++){
        int n0 = wv*64 + a2*16 + lg*4;
        float4 bv = *(const float4*)(b1 + e*HH + n0);
        #pragma unroll
        for (int tt = 0; tt < 4; tt++){
            int tok = tt*16 + ll;
            float h0 = acc[a2][tt][0] + bv.x; h0 = h0 > 0.f ? h0 : 0.f;
            float h1 = acc[a2][tt][1] + bv.y; h1 = h1 > 0.f ? h1 : 0.f;
            float h2 = acc[a2][tt][2] + bv.z; h2 = h2 > 0.f ? h2 : 0.f;
            float h3 = acc[a2][tt][3] + bv.w; h3 = h3 > 0.f ? h3 : 0.f;
            uint2 pk;
            pk.x = (unsigned)f2bf(h0) | ((unsigned)f2bf(h1) << 16);
            pk.y = (unsigned)f2bf(h2) | ((unsigned)f2bf(h3) << 16);
            int bofs = (n0*2) ^ ((tok & 7) << 4);
            *(uint2*)((char*)AH + tok*1024 + bofs) = pk;
            acc[a2][tt] = (f32x4)0.f;
        }
    }
    __syncthreads();

    // ---- layer 2: acc[b][tt] += h-frag(tt,kc) @ W2-frag(b,kc) ----
    {
        const unsigned short* Wb = W2f + ((size_t)e << 18) + (size_t)wv*32768;
        bf16x8 f0[4], f1[4];
        #pragma unroll
        for (int b_ = 0; b_ < 4; b_++)
            f0[b_] = *(const bf16x8*)(Wb + b_*8192 + lane*8);
        #pragma unroll 1
        for (int kc = 0; kc < 16; kc += 2){
            #pragma unroll
            for (int b_ = 0; b_ < 4; b_++)
                f1[b_] = *(const bf16x8*)(Wb + b_*8192 + (kc+1)*512 + lane*8);
            {
                bf16x8 ah[4];
                #pragma unroll
                for (int tt = 0; tt < 4; tt++){
                    int tok = tt*16 + ll;
                    int bofs = (64*kc + 16*lg) ^ ((tok & 7) << 4);
                    ah[tt] = *(const bf16x8*)((char*)AH + tok*1024 + bofs);
                }
                #pragma unroll
                for (int b_ = 0; b_ < 4; b_++)
                    #pragma unroll
                    for (int tt = 0; tt < 4; tt++)
                        acc[b_][tt] = __builtin_amdgcn_mfma_f32_16x16x32_bf16(ah[tt], f0[b_], acc[b_][tt], 0, 0, 0);
            }
            if (kc + 2 < 16){
                #pragma unroll
                for (int b_ = 0; b_ < 4; b_++)
                    f0[b_] = *(const bf16x8*)(Wb + b_*8192 + (kc+2)*512 + lane*8);
            }
            {
                bf16x8 ah[4];
                #pragma unroll
                for (int tt = 0; tt < 4; tt++){
                    int tok = tt*16 + ll;
                    int bofs = (64*(kc+1) + 16*lg) ^ ((tok & 7) << 4);
                    ah[tt] = *(const bf16x8*)((char*)AH + tok*1024 + bofs);
                }
                #pragma unroll
                for (int b_ = 0; b_ < 4; b_++)
                    #pragma unroll
                    for (int tt = 0; tt < 4; tt++)
                        acc[b_][tt] = __builtin_amdgcn_mfma_f32_16x16x32_bf16(ah[tt], f1[b_], acc[b_][tt], 0, 0, 0);
            }
        }
    }

    // ---- epilogue: top-1 -> y (fp32 plain), top-2 -> y2h (bf16, weighted) ----
    float bb[4];
    #pragma unroll
    for (int b_ = 0; b_ < 4; b_++)
        bb[b_] = b2[e*DD + wv*64 + b_*16 + ll];

    #pragma unroll
    for (int tt = 0; tt < 4; tt++){
        #pragma unroll
        for (int i = 0; i < 4; i++){
            int rl = tt*16 + lg*4 + i;
            int gr = r0 + rl;
            if (gr < cnt){
                int   v  = gsl[e*CAP + gr];
                int   tk = v & 0xFFFFF;
                float w  = wts[e*CAP + gr];
                if (v >> 20){
                    unsigned short* dst = y2h + (size_t)tk * DD;
                    #pragma unroll
                    for (int b_ = 0; b_ < 4; b_++){
                        int col = wv*64 + b_*16 + ll;
                        dst[col] = f2bf(w * (acc[b_][tt][i] + bb[b_]));
                    }
                } else {
                    float* dst = y + (size_t)tk * DD;
                    #pragma unroll
                    for (int b_ = 0; b_ < 4; b_++){
                        int col = wv*64 + b_*16 + ll;
                        dst[col] = w * (acc[b_][tt][i] + bb[b_]);
                    }
                }
            }
        }
    }
}

// ---------------- combine: y = [k1]y + [k2]bf16(y2), or passthrough x ----------------
__global__ __launch_bounds__(256) void k_comb(
    const float* __restrict__ x, const unsigned short* __restrict__ y2h,
    const unsigned char* __restrict__ flags, float* __restrict__ y)
{
    const float4* x4  = (const float4*)x;
    const uint2*  y24 = (const uint2*)y2h;
    float4* y4 = (float4*)y;
    int nthreads = gridDim.x * 256;
    int g = blockIdx.x * 256 + threadIdx.x;
    #pragma unroll 1
    for (long long idx = g; idx < (long long)BT * 128; idx += nthreads){
        int t = (int)(idx >> 7);
        int f = flags[t];
        if (f == 3){
            float4 a = y4[idx];
            uint2 p = y24[idx];
            a.x += bf2f((unsigned short)(p.x & 0xFFFF));
            a.y += bf2f((unsigned short)(p.x >> 16));
            a.z += bf2f((unsigned short)(p.y & 0xFFFF));
            a.w += bf2f((unsigned short)(p.y >> 16));
            y4[idx] = a;
        } else if (f == 2){
            uint2 p = y24[idx];
            float4 a;
            a.x = bf2f((unsigned short)(p.x & 0xFFFF));
            a.y = bf2f((unsigned short)(p.x >> 16));
            a.z = bf2f((unsigned short)(p.y & 0xFFFF));
            a.w = bf2f((unsigned short)(p.y >> 16));
            y4[idx] = a;
        } else if (f == 0){
            y4[idx] = x4[idx];
        } // f == 1: y already correct
    }
}

extern "C" void kernel_launch(void* const* d_in, const int* in_sizes, int n_in,
                              void* d_out, int out_size, void* d_ws, size_t ws_size,
                              hipStream_t stream)
{
    const float* x  = (const float*)d_in[0];
    const float* Wg = (const float*)d_in[1];
    const float* W1 = (const float*)d_in[2];
    const float* b1 = (const float*)d_in[3];
    const float* W2 = (const float*)d_in[4];
    const float* b2 = (const float*)d_in[5];
    float* y = (float*)d_out;

    char* ws = (char*)d_ws;
    unsigned short* W1f = (unsigned short*)(ws);
    unsigned short* W2f = (unsigned short*)(ws + 16777216);
    int*   counts = (int*)  (ws + 33554432);
    int*   gsl    = (int*)  (ws + 33554432 + 256);
    float* wts    = (float*)(ws + 33554432 + 256 + 655360);
    unsigned char* flags = (unsigned char*)(ws + 33554432 + 256 + 2*655360);
    unsigned short* xb16 = (unsigned short*)(ws + 35651584);                // 67.1 MB
    unsigned short* y2h  = (unsigned short*)(ws + 35651584 + 67108864);     // 67.1 MB

    hipMemsetAsync(counts, 0, 256, stream);
    hipLaunchKernelGGL(k_prep, dim3(512 + BT/64), dim3(256), 0, stream,
                       x, Wg, W1, W2, W1f, W2f, counts, gsl, wts, flags, xb16);
    hipLaunchKernelGGL(k_ffn,  dim3(NE*NRB), dim3(512), 0, stream,
                       xb16, W1f, W2f, b1, b2, counts, gsl, wts, y, y2h);
    hipLaunchKernelGGL(k_comb, dim3(2048), dim3(256), 0, stream, x, y2h, flags, y);
}

// Round 12
// 405.461 us; speedup vs baseline: 1.0948x; 1.0398x over previous
//
#include <hip/hip_runtime.h>
#include <hip/hip_bf16.h>

#define BT 65536
#define DD 512
#define HH 512
#define NE 32
#define CAP 5120
#define BM 64
#define NRB 80   /* CAP/BM */

typedef float  f32x4  __attribute__((ext_vector_type(4)));
typedef short  bf16x8 __attribute__((ext_vector_type(8)));

__device__ __forceinline__ unsigned short f2bf(float f){
    unsigned int u = __builtin_bit_cast(unsigned int, f);
    unsigned int r = (u + 0x7fffu + ((u >> 16) & 1u)) >> 16;
    return (unsigned short)r;
}
__device__ __forceinline__ float bf2f(unsigned short h){
    unsigned int u = ((unsigned int)h) << 16;
    return __builtin_bit_cast(float, u);
}

// ---------------- prep: blocks [0,256) = gate (Wg in LDS); [256,768) = weight conv ----------------
__global__ __launch_bounds__(256) void k_prep(
    const float* __restrict__ x, const float* __restrict__ Wg,
    const float* __restrict__ W1, const float* __restrict__ W2,
    unsigned short* __restrict__ W1f, unsigned short* __restrict__ W2f,
    int* __restrict__ counts, int* __restrict__ gsl, float* __restrict__ wts,
    unsigned char* __restrict__ flags, unsigned short* __restrict__ xb16)
{
    __shared__ float WgS[DD * NE];      // 64 KB
    __shared__ int lcnt[NE], lbase[NE];

    int tid = threadIdx.x;

    if (blockIdx.x >= 256){
        // ---------------- weight convert (float4-vectorized) ----------------
        // W[e][k][n] fp32 -> Wf[e][nt(32)][kc(16)][lane(64)][8] bf16; fragment (nt,kc):
        // lane holds W[k = kc*32 + (lane>>4)*8 + j][n = nt*16 + (lane&15)].
        int b = blockIdx.x - 256;              // 0..511
        int w = b >> 8;
        int e = (b >> 3) & 31;
        int kq = b & 7;
        const float* src = (w ? W2 : W1) + ((size_t)e << 18);
        unsigned short* dst = (w ? W2f : W1f) + ((size_t)e << 18);
        int n4 = (tid & 127) * 4;
        int kh = tid >> 7;                     // 0..1
        #pragma unroll 1
        for (int kg = 0; kg < 4; kg++){
            int k0 = kq*64 + (kg*2 + kh)*8;
            float4 rows[8];
            #pragma unroll
            for (int j = 0; j < 8; j++)
                rows[j] = *(const float4*)&src[(size_t)(k0 + j)*512 + n4];
            unsigned short v0[8], v1[8], v2[8], v3[8];
            #pragma unroll
            for (int j = 0; j < 8; j++){
                v0[j] = f2bf(rows[j].x); v1[j] = f2bf(rows[j].y);
                v2[j] = f2bf(rows[j].z); v3[j] = f2bf(rows[j].w);
            }
            int kc = k0 >> 5, lb = ((k0 >> 3) & 3)*16;
            #pragma unroll
            for (int m = 0; m < 4; m++){
                int n = n4 + m;
                int nt = n >> 4, ln = lb + (n & 15);
                const unsigned short* vv = (m==0)?v0:(m==1)?v1:(m==2)?v2:v3;
                *(bf16x8*)(dst + (((size_t)(nt*16 + kc)*64 + ln) << 3)) = *(const bf16x8*)vv;
            }
        }
        return;
    }

    // ---------------- gate v8: thread=token, Wg broadcast from LDS ----------------
    int tok = blockIdx.x * 256 + tid;
    const float* xr = x + (size_t)tok * DD;

    // stage Wg (coalesced): 16 x 256 threads x 16B = 64KB
    #pragma unroll
    for (int i = 0; i < 16; i++){
        int f = i*1024 + tid*4;
        *(float4*)&WgS[f] = *(const float4*)&Wg[f];
    }
    if (tid < NE) lcnt[tid] = 0;
    __syncthreads();

    float acc[NE];
    #pragma unroll
    for (int n = 0; n < NE; n++) acc[n] = 0.f;

    float4 xa = *(const float4*)(xr);
    float4 xb = *(const float4*)(xr + 4);
    #pragma unroll 1
    for (int d = 0; d < DD; d += 8){
        int dn = (d + 8 < DD) ? (d + 8) : 0;
        float4 na = *(const float4*)(xr + dn);
        float4 nb = *(const float4*)(xr + dn + 4);
        // byproduct: bf16 copy of x for the FFN's gather
        uint4 pk;
        pk.x = (unsigned)f2bf(xa.x) | ((unsigned)f2bf(xa.y) << 16);
        pk.y = (unsigned)f2bf(xa.z) | ((unsigned)f2bf(xa.w) << 16);
        pk.z = (unsigned)f2bf(xb.x) | ((unsigned)f2bf(xb.y) << 16);
        pk.w = (unsigned)f2bf(xb.z) | ((unsigned)f2bf(xb.w) << 16);
        *(uint4*)(xb16 + (size_t)tok*DD + d) = pk;
        #pragma unroll
        for (int j = 0; j < 8; j++){
            float xv = (j < 4) ? ((j==0)?xa.x:(j==1)?xa.y:(j==2)?xa.z:xa.w)
                               : ((j==4)?xb.x:(j==5)?xb.y:(j==6)?xb.z:xb.w);
            const float4* wr = (const float4*)&WgS[(d + j)*NE];   // LDS broadcast
            #pragma unroll
            for (int q = 0; q < 8; q++){
                float4 w4 = wr[q];
                acc[q*4+0] = fmaf(xv, w4.x, acc[q*4+0]);
                acc[q*4+1] = fmaf(xv, w4.y, acc[q*4+1]);
                acc[q*4+2] = fmaf(xv, w4.z, acc[q*4+2]);
                acc[q*4+3] = fmaf(xv, w4.w, acc[q*4+3]);
            }
        }
        xa = na; xb = nb;
    }

    // top-3 in fp32 (strict > keeps lowest index on ties, matching lax.top_k)
    float v1 = -1e30f; int i1 = -1;
    #pragma unroll
    for (int n = 0; n < NE; n++) if (acc[n] > v1){ v1 = acc[n]; i1 = n; }
    float v2 = -1e30f; int i2 = -1;
    #pragma unroll
    for (int n = 0; n < NE; n++) if (n != i1 && acc[n] > v2){ v2 = acc[n]; i2 = n; }
    float v3 = -1e30f;
    #pragma unroll
    for (int n = 0; n < NE; n++) if (n != i1 && n != i2 && acc[n] > v3) v3 = acc[n];

    float w1, w2;
    if (v2 - v3 >= 1e-4f){
        double ex  = exp((double)v2 - (double)v1);
        double inv = 1.0 / (1.0 + ex);
        w1 = (float)inv; w2 = (float)(ex * inv);
    } else {
        // rare (~1e-3): resolve the {top2} set among near-tie candidates in fp64 (global Wg).
        float thresh = v2 - 1e-3f;
        unsigned cmask = 0u;
        #pragma unroll
        for (int n = 0; n < NE; n++) cmask |= (acc[n] >= thresh) ? (1u << n) : 0u;

        double dv1 = -1.0e300, dv2 = -1.0e300; int di1 = -1, di2 = -1;
        #pragma unroll 1
        for (int n = 0; n < NE; n++){
            if (!((cmask >> n) & 1u)) continue;
            double s0 = 0.0, s1 = 0.0, s2 = 0.0, s3 = 0.0;
            #pragma unroll 4
            for (int d = 0; d < DD; d += 4){
                s0 = fma((double)xr[d+0], (double)Wg[(size_t)(d+0)*NE + n], s0);
                s1 = fma((double)xr[d+1], (double)Wg[(size_t)(d+1)*NE + n], s1);
                s2 = fma((double)xr[d+2], (double)Wg[(size_t)(d+2)*NE + n], s2);
                s3 = fma((double)xr[d+3], (double)Wg[(size_t)(d+3)*NE + n], s3);
            }
            double s = (s0 + s1) + (s2 + s3);
            if (s > dv1){ dv2 = dv1; di2 = di1; dv1 = s; di1 = n; }
            else if (s > dv2){ dv2 = s; di2 = n; }
        }
        i1 = di1; i2 = di2;
        double ex  = exp(dv2 - dv1);
        double inv = 1.0 / (1.0 + ex);
        w1 = (float)inv; w2 = (float)(ex * inv);
    }

    // two-level slot assignment
    int s1 = atomicAdd(&lcnt[i1], 1);
    int s2 = atomicAdd(&lcnt[i2], 1);
    __syncthreads();
    if (tid < NE && lcnt[tid] > 0) lbase[tid] = atomicAdd(&counts[tid], lcnt[tid]);
    __syncthreads();
    int g1 = lbase[i1] + s1;
    int g2 = lbase[i2] + s2;
    bool k1 = g1 < CAP, k2 = g2 < CAP;
    if (k1){ gsl[i1*CAP + g1] = tok;               wts[i1*CAP + g1] = w1; }
    if (k2){ gsl[i2*CAP + g2] = tok | (1 << 20);   wts[i2*CAP + g2] = w2; }
    flags[tok] = (unsigned char)((k1 ? 1 : 0) | (k2 ? 2 : 0));
}

// ---------------- fused expert FFN: BM=64, bf16-x staging, split-destination epilogue ----------------
__global__ __launch_bounds__(512, 4) void k_ffn(
    const unsigned short* __restrict__ xb16,
    const unsigned short* __restrict__ W1f,
    const unsigned short* __restrict__ W2f,
    const float* __restrict__ b1, const float* __restrict__ b2,
    const int* __restrict__ counts,
    const int* __restrict__ gsl, const float* __restrict__ wts,
    float* __restrict__ y, unsigned short* __restrict__ y2h)
{
    __shared__ unsigned char AH[64 * 1024];   // [tok(64)][512 bf16], 16B-chunk XOR swizzle ((tok&7)<<4)

    int p  = blockIdx.x;
    int s  = p >> 3;
    int e  = ((s / NRB) << 3) | (p & 7);
    int rb = s % NRB;

    int cnt = counts[e]; if (cnt > CAP) cnt = CAP;
    int r0 = rb * BM;
    if (r0 >= cnt) return;

    int tid  = threadIdx.x;
    int lane = tid & 63;
    int wv   = tid >> 6;      // 8 waves: wave owns hidden/output cols [wv*64, wv*64+64)
    int lg   = lane >> 4;
    int ll   = lane & 15;

    // ---- stage X from bf16 copy (16B chunks, no conversion) ----
    {
        int row = tid >> 3, seg = tid & 7;
        int gr  = r0 + row;
        char* rowb = (char*)AH + row * 1024;
        int rsw = (row & 7) << 4;
        if (gr < cnt){
            int tk = gsl[e*CAP + gr] & 0xFFFFF;
            const uint4* src = (const uint4*)(xb16 + (size_t)tk*DD + seg*64);
            #pragma unroll
            for (int j = 0; j < 8; j++){
                uint4 v = src[j];
                int chunk = seg*8 + j;
                *(uint4*)(rowb + ((chunk << 4) ^ rsw)) = v;
            }
        } else {
            uint4 zz; zz.x = zz.y = zz.z = zz.w = 0u;
            #pragma unroll
            for (int j = 0; j < 8; j++){
                int chunk = seg*8 + j;
                *(uint4*)(rowb + ((chunk << 4) ^ rsw)) = zz;
            }
        }
    }
    __syncthreads();

    f32x4 acc[4][4];
    #pragma unroll
    for (int a2 = 0; a2 < 4; a2++)
        #pragma unroll
        for (int tt = 0; tt < 4; tt++)
            acc[a2][tt] = (f32x4)0.f;

    // ---- layer 1 (swapped): acc[a][tt] += W1^T-frag(a,c) x X-frag(tt,c) ----
    {
        const unsigned short* Wa = W1f + ((size_t)e << 18) + (size_t)wv*32768;
        bf16x8 f0[4], f1[4];
        #pragma unroll
        for (int a2 = 0; a2 < 4; a2++)
            f0[a2] = *(const bf16x8*)(Wa + a2*8192 + lane*8);
        #pragma unroll 1
        for (int c = 0; c < 16; c += 2){
            #pragma unroll
            for (int a2 = 0; a2 < 4; a2++)
                f1[a2] = *(const bf16x8*)(Wa + a2*8192 + (c+1)*512 + lane*8);
            {
                bf16x8 bx[4];
                #pragma unroll
                for (int tt = 0; tt < 4; tt++){
                    int tok = tt*16 + ll;
                    int bofs = (64*c + 16*lg) ^ ((tok & 7) << 4);
                    bx[tt] = *(const bf16x8*)((char*)AH + tok*1024 + bofs);
                }
                __builtin_amdgcn_s_setprio(1);
                #pragma unroll
                for (int a2 = 0; a2 < 4; a2++)
                    #pragma unroll
                    for (int tt = 0; tt < 4; tt++)
                        acc[a2][tt] = __builtin_amdgcn_mfma_f32_16x16x32_bf16(f0[a2], bx[tt], acc[a2][tt], 0, 0, 0);
                __builtin_amdgcn_s_setprio(0);
            }
            if (c + 2 < 16){
                #pragma unroll
                for (int a2 = 0; a2 < 4; a2++)
                    f0[a2] = *(const bf16x8*)(Wa + a2*8192 + (c+2)*512 + lane*8);
            }
            {
                bf16x8 bx[4];
                #pragma unroll
                for (int tt = 0; tt < 4; tt++){
                    int tok = tt*16 + ll;
                    int bofs = (64*(c+1) + 16*lg) ^ ((tok & 7) << 4);
                    bx[tt] = *(const bf16x8*)((char*)AH + tok*1024 + bofs);
                }
                __builtin_amdgcn_s_setprio(1);
                #pragma unroll
                for (int a2 = 0; a2 < 4; a2++)
                    #pragma unroll
                    for (int tt = 0; tt < 4; tt++)
                        acc[a2][tt] = __builtin_amdgcn_mfma_f32_16x16x32_bf16(f1[a2], bx[tt], acc[a2][tt], 0, 0, 0);
                __builtin_amdgcn_s_setprio(0);
            }
        }
    }
    __syncthreads();

    // ---- h = relu(acc + b1) -> AH as h[tok][n], packed 8B writes ----
    #pragma unroll
    for (int a2 = 0; a2 < 4; a2++){
        int n0 = wv*64 + a2*16 + lg*4;
        float4 bv = *(const float4*)(b1 + e*HH + n0);
        #pragma unroll
        for (int tt = 0; tt < 4; tt++){
            int tok = tt*16 + ll;
            float h0 = acc[a2][tt][0] + bv.x; h0 = h0 > 0.f ? h0 : 0.f;
            float h1 = acc[a2][tt][1] + bv.y; h1 = h1 > 0.f ? h1 : 0.f;
            float h2 = acc[a2][tt][2] + bv.z; h2 = h2 > 0.f ? h2 : 0.f;
            float h3 = acc[a2][tt][3] + bv.w; h3 = h3 > 0.f ? h3 : 0.f;
            uint2 pk;
            pk.x = (unsigned)f2bf(h0) | ((unsigned)f2bf(h1) << 16);
            pk.y = (unsigned)f2bf(h2) | ((unsigned)f2bf(h3) << 16);
            int bofs = (n0*2) ^ ((tok & 7) << 4);
            *(uint2*)((char*)AH + tok*1024 + bofs) = pk;
            acc[a2][tt] = (f32x4)0.f;
        }
    }
    __syncthreads();

    // ---- layer 2: acc[b][tt] += h-frag(tt,kc) @ W2-frag(b,kc) ----
    {
        const unsigned short* Wb = W2f + ((size_t)e << 18) + (size_t)wv*32768;
        bf16x8 f0[4], f1[4];
        #pragma unroll
        for (int b_ = 0; b_ < 4; b_++)
            f0[b_] = *(const bf16x8*)(Wb + b_*8192 + lane*8);
        #pragma unroll 1
        for (int kc = 0; kc < 16; kc += 2){
            #pragma unroll
            for (int b_ = 0; b_ < 4; b_++)
                f1[b_] = *(const bf16x8*)(Wb + b_*8192 + (kc+1)*512 + lane*8);
            {
                bf16x8 ah[4];
                #pragma unroll
                for (int tt = 0; tt < 4; tt++){
                    int tok = tt*16 + ll;
                    int bofs = (64*kc + 16*lg) ^ ((tok & 7) << 4);
                    ah[tt] = *(const bf16x8*)((char*)AH + tok*1024 + bofs);
                }
                __builtin_amdgcn_s_setprio(1);
                #pragma unroll
                for (int b_ = 0; b_ < 4; b_++)
                    #pragma unroll
                    for (int tt = 0; tt < 4; tt++)
                        acc[b_][tt] = __builtin_amdgcn_mfma_f32_16x16x32_bf16(ah[tt], f0[b_], acc[b_][tt], 0, 0, 0);
                __builtin_amdgcn_s_setprio(0);
            }
            if (kc + 2 < 16){
                #pragma unroll
                for (int b_ = 0; b_ < 4; b_++)
                    f0[b_] = *(const bf16x8*)(Wb + b_*8192 + (kc+2)*512 + lane*8);
            }
            {
                bf16x8 ah[4];
                #pragma unroll
                for (int tt = 0; tt < 4; tt++){
                    int tok = tt*16 + ll;
                    int bofs = (64*(kc+1) + 16*lg) ^ ((tok & 7) << 4);
                    ah[tt] = *(const bf16x8*)((char*)AH + tok*1024 + bofs);
                }
                __builtin_amdgcn_s_setprio(1);
                #pragma unroll
                for (int b_ = 0; b_ < 4; b_++)
                    #pragma unroll
                    for (int tt = 0; tt < 4; tt++)
                        acc[b_][tt] = __builtin_amdgcn_mfma_f32_16x16x32_bf16(ah[tt], f1[b_], acc[b_][tt], 0, 0, 0);
                __builtin_amdgcn_s_setprio(0);
            }
        }
    }

    // ---- epilogue: top-1 -> y (fp32 plain), top-2 -> y2h (bf16, weighted) ----
    float bb[4];
    #pragma unroll
    for (int b_ = 0; b_ < 4; b_++)
        bb[b_] = b2[e*DD + wv*64 + b_*16 + ll];

    #pragma unroll
    for (int tt = 0; tt < 4; tt++){
        #pragma unroll
        for (int i = 0; i < 4; i++){
            int rl = tt*16 + lg*4 + i;
            int gr = r0 + rl;
            if (gr < cnt){
                int   v  = gsl[e*CAP + gr];
                int   tk = v & 0xFFFFF;
                float w  = wts[e*CAP + gr];
                if (v >> 20){
                    unsigned short* dst = y2h + (size_t)tk * DD;
                    #pragma unroll
                    for (int b_ = 0; b_ < 4; b_++){
                        int col = wv*64 + b_*16 + ll;
                        dst[col] = f2bf(w * (acc[b_][tt][i] + bb[b_]));
                    }
                } else {
                    float* dst = y + (size_t)tk * DD;
                    #pragma unroll
                    for (int b_ = 0; b_ < 4; b_++){
                        int col = wv*64 + b_*16 + ll;
                        dst[col] = w * (acc[b_][tt][i] + bb[b_]);
                    }
                }
            }
        }
    }
}

// ---------------- combine: y = [k1]y + [k2]bf16(y2), or passthrough x ----------------
__global__ __launch_bounds__(256) void k_comb(
    const float* __restrict__ x, const unsigned short* __restrict__ y2h,
    const unsigned char* __restrict__ flags, float* __restrict__ y)
{
    const float4* x4  = (const float4*)x;
    const uint2*  y24 = (const uint2*)y2h;
    float4* y4 = (float4*)y;
    int nthreads = gridDim.x * 256;
    int g = blockIdx.x * 256 + threadIdx.x;
    #pragma unroll 1
    for (long long idx = g; idx < (long long)BT * 128; idx += nthreads){
        int t = (int)(idx >> 7);
        int f = flags[t];
        if (f == 3){
            float4 a = y4[idx];
            uint2 p = y24[idx];
            a.x += bf2f((unsigned short)(p.x & 0xFFFF));
            a.y += bf2f((unsigned short)(p.x >> 16));
            a.z += bf2f((unsigned short)(p.y & 0xFFFF));
            a.w += bf2f((unsigned short)(p.y >> 16));
            y4[idx] = a;
        } else if (f == 2){
            uint2 p = y24[idx];
            float4 a;
            a.x = bf2f((unsigned short)(p.x & 0xFFFF));
            a.y = bf2f((unsigned short)(p.x >> 16));
            a.z = bf2f((unsigned short)(p.y & 0xFFFF));
            a.w = bf2f((unsigned short)(p.y >> 16));
            y4[idx] = a;
        } else if (f == 0){
            y4[idx] = x4[idx];
        } // f == 1: y already correct
    }
}

extern "C" void kernel_launch(void* const* d_in, const int* in_sizes, int n_in,
                              void* d_out, int out_size, void* d_ws, size_t ws_size,
                              hipStream_t stream)
{
    const float* x  = (const float*)d_in[0];
    const float* Wg = (const float*)d_in[1];
    const float* W1 = (const float*)d_in[2];
    const float* b1 = (const float*)d_in[3];
    const float* W2 = (const float*)d_in[4];
    const float* b2 = (const float*)d_in[5];
    float* y = (float*)d_out;

    char* ws = (char*)d_ws;
    unsigned short* W1f = (unsigned short*)(ws);
    unsigned short* W2f = (unsigned short*)(ws + 16777216);
    int*   counts = (int*)  (ws + 33554432);
    int*   gsl    = (int*)  (ws + 33554432 + 256);
    float* wts    = (float*)(ws + 33554432 + 256 + 655360);
    unsigned char* flags = (unsigned char*)(ws + 33554432 + 256 + 2*655360);
    unsigned short* xb16 = (unsigned short*)(ws + 35651584);                // 67.1 MB
    unsigned short* y2h  = (unsigned short*)(ws + 35651584 + 67108864);     // 67.1 MB

    hipMemsetAsync(counts, 0, 256, stream);
    hipLaunchKernelGGL(k_prep, dim3(256 + 512), dim3(256), 0, stream,
                       x, Wg, W1, W2, W1f, W2f, counts, gsl, wts, flags, xb16);
    hipLaunchKernelGGL(k_ffn,  dim3(NE*NRB), dim3(512), 0, stream,
                       xb16, W1f, W2f, b1, b2, counts, gsl, wts, y, y2h);
    hipLaunchKernelGGL(k_comb, dim3(2048), dim3(256), 0, stream, x, y2h, flags, y);
}

// Round 14
// 394.676 us; speedup vs baseline: 1.1247x; 1.0273x over previous
//
#include <hip/hip_runtime.h>
#include <hip/hip_bf16.h>

#define BT 65536
#define DD 512
#define HH 512
#define NE 32
#define CAP 5120
#define BM 64
#define NRB 80   /* CAP/BM */

typedef float  f32x4  __attribute__((ext_vector_type(4)));
typedef short  bf16x8 __attribute__((ext_vector_type(8)));

__device__ __forceinline__ unsigned short f2bf(float f){
    unsigned int u = __builtin_bit_cast(unsigned int, f);
    unsigned int r = (u + 0x7fffu + ((u >> 16) & 1u)) >> 16;
    return (unsigned short)r;
}
__device__ __forceinline__ float bf2f(unsigned short h){
    unsigned int u = ((unsigned int)h) << 16;
    return __builtin_bit_cast(float, u);
}

// ---------------- Wg -> hi/lo MFMA A-fragments (W^T rows = experts) ----------------
// WgHf/WgLf[ef(2)][kc(16)][lane(64)][8]: lane holds Wg[d = kc*32+(lane>>4)*8+j][e = ef*16+(lane&15)]
__global__ __launch_bounds__(256) void k_wgprep(
    const float* __restrict__ Wg,
    unsigned short* __restrict__ WgHf, unsigned short* __restrict__ WgLf)
{
    int t = threadIdx.x;
    #pragma unroll
    for (int i = 0; i < 8; i++){
        int entry = i*256 + t;              // 0..2047 = ef*1024 + kc*64 + ln
        int ln = entry & 63;
        unsigned short h[8], l[8];
        #pragma unroll
        for (int j = 0; j < 8; j++){
            int d = ((entry >> 6) & 15)*32 + (ln >> 4)*8 + j;
            int e = (entry >> 10)*16 + (ln & 15);
            float v = Wg[d*NE + e];
            unsigned short hi = f2bf(v);
            h[j] = hi;
            l[j] = f2bf(v - bf2f(hi));
        }
        *(bf16x8*)(WgHf + (size_t)entry*8) = *(bf16x8*)h;
        *(bf16x8*)(WgLf + (size_t)entry*8) = *(bf16x8*)l;
    }
}

// ---------------- prep: blocks [0,2048) = MFMA gate (32 tok); [2048,2560) = weight conv ----------------
__global__ __launch_bounds__(256) void k_prep(
    const float* __restrict__ x, const float* __restrict__ Wg,
    const float* __restrict__ W1, const float* __restrict__ W2,
    const unsigned short* __restrict__ WgHf, const unsigned short* __restrict__ WgLf,
    unsigned short* __restrict__ W1f, unsigned short* __restrict__ W2f,
    int* __restrict__ counts, int* __restrict__ gsl, float* __restrict__ wts,
    unsigned char* __restrict__ flags, unsigned short* __restrict__ xb16)
{
    __shared__ unsigned char XH[32 * 1024];   // x_hi tile [tok(32)][512 bf16], ffn swizzle
    __shared__ unsigned char XL[32 * 1024];   // x_lo tile, same layout
    __shared__ float lg2[32 * 33];            // logits [tok][expert], padded
    __shared__ int lcnt[NE], lbase[NE];

    int tid = threadIdx.x;

    if (blockIdx.x >= 2048){
        // ---------------- weight convert (float4-vectorized) ----------------
        int b = blockIdx.x - 2048;             // 0..511
        int w = b >> 8;
        int e = (b >> 3) & 31;
        int kq = b & 7;
        const float* src = (w ? W2 : W1) + ((size_t)e << 18);
        unsigned short* dst = (w ? W2f : W1f) + ((size_t)e << 18);
        int n4 = (tid & 127) * 4;
        int kh = tid >> 7;
        #pragma unroll 1
        for (int kg = 0; kg < 4; kg++){
            int k0 = kq*64 + (kg*2 + kh)*8;
            float4 rows[8];
            #pragma unroll
            for (int j = 0; j < 8; j++)
                rows[j] = *(const float4*)&src[(size_t)(k0 + j)*512 + n4];
            unsigned short v0[8], v1[8], v2[8], v3[8];
            #pragma unroll
            for (int j = 0; j < 8; j++){
                v0[j] = f2bf(rows[j].x); v1[j] = f2bf(rows[j].y);
                v2[j] = f2bf(rows[j].z); v3[j] = f2bf(rows[j].w);
            }
            int kc = k0 >> 5, lb = ((k0 >> 3) & 3)*16;
            #pragma unroll
            for (int m = 0; m < 4; m++){
                int n = n4 + m;
                int nt = n >> 4, ln = lb + (n & 15);
                const unsigned short* vv = (m==0)?v0:(m==1)?v1:(m==2)?v2:v3;
                *(bf16x8*)(dst + (((size_t)(nt*16 + kc)*64 + ln) << 3)) = *(const bf16x8*)vv;
            }
        }
        return;
    }

    // ---------------- gate v9: split-bf16 MFMA logits ----------------
    int t0 = blockIdx.x * 32;                  // first token of block

    // stage x: 8 threads/row; hi+lo bf16 tiles + xb16 byproduct
    {
        int row = tid >> 3, seg = tid & 7;
        int tok = t0 + row;
        const float* sx = x + (size_t)tok*DD + seg*64;
        char* rbH = (char*)XH + row*1024;
        char* rbL = (char*)XL + row*1024;
        int rsw = (row & 7) << 4;
        #pragma unroll
        for (int jj = 0; jj < 8; jj++){
            float4 a = *(const float4*)(sx + jj*8);
            float4 b = *(const float4*)(sx + jj*8 + 4);
            unsigned short h[8], l[8];
            h[0]=f2bf(a.x); h[1]=f2bf(a.y); h[2]=f2bf(a.z); h[3]=f2bf(a.w);
            h[4]=f2bf(b.x); h[5]=f2bf(b.y); h[6]=f2bf(b.z); h[7]=f2bf(b.w);
            l[0]=f2bf(a.x-bf2f(h[0])); l[1]=f2bf(a.y-bf2f(h[1]));
            l[2]=f2bf(a.z-bf2f(h[2])); l[3]=f2bf(a.w-bf2f(h[3]));
            l[4]=f2bf(b.x-bf2f(h[4])); l[5]=f2bf(b.y-bf2f(h[5]));
            l[6]=f2bf(b.z-bf2f(h[6])); l[7]=f2bf(b.w-bf2f(h[7]));
            int chunk = seg*8 + jj;
            *(bf16x8*)(rbH + ((chunk << 4) ^ rsw)) = *(bf16x8*)h;
            *(bf16x8*)(rbL + ((chunk << 4) ^ rsw)) = *(bf16x8*)l;
            *(bf16x8*)(xb16 + (size_t)tok*DD + seg*64 + jj*8) = *(bf16x8*)h;
        }
    }
    if (tid < NE) lcnt[tid] = 0;
    __syncthreads();

    // MFMA: wave wv handles expert-frag ef=wv>>1, token-frag tf=wv&1
    {
        int lane = tid & 63;
        int wv   = tid >> 6;
        int lg   = lane >> 4, ll = lane & 15;
        int ef = wv >> 1, tf = wv & 1;
        const unsigned short* Ah = WgHf + ef*8192;
        const unsigned short* Al = WgLf + ef*8192;
        int tokl = tf*16 + ll;
        f32x4 acc = (f32x4)0.f;
        #pragma unroll 1
        for (int kc = 0; kc < 16; kc++){
            bf16x8 ah = *(const bf16x8*)(Ah + kc*512 + lane*8);
            bf16x8 al = *(const bf16x8*)(Al + kc*512 + lane*8);
            int bofs = (64*kc + 16*lg) ^ ((tokl & 7) << 4);
            bf16x8 bh = *(const bf16x8*)((char*)XH + tokl*1024 + bofs);
            bf16x8 bl = *(const bf16x8*)((char*)XL + tokl*1024 + bofs);
            acc = __builtin_amdgcn_mfma_f32_16x16x32_bf16(ah, bh, acc, 0, 0, 0);
            acc = __builtin_amdgcn_mfma_f32_16x16x32_bf16(ah, bl, acc, 0, 0, 0);
            acc = __builtin_amdgcn_mfma_f32_16x16x32_bf16(al, bh, acc, 0, 0, 0);
        }
        #pragma unroll
        for (int i = 0; i < 4; i++)
            lg2[tokl*33 + ef*16 + lg*4 + i] = acc[i];
    }
    __syncthreads();

    // selection: one thread per token; barriers kept in UNIFORM control flow
    float w1 = 0.f, w2 = 0.f;
    int i1 = 0, i2 = 0, s1 = 0, s2 = 0;
    bool act = (tid < 32);
    if (act){
        int tok = t0 + tid;
        float acc[NE];
        #pragma unroll
        for (int n = 0; n < NE; n++) acc[n] = lg2[tid*33 + n];

        float v1 = -1e30f; i1 = -1;
        #pragma unroll
        for (int n = 0; n < NE; n++) if (acc[n] > v1){ v1 = acc[n]; i1 = n; }
        float v2 = -1e30f; i2 = -1;
        #pragma unroll
        for (int n = 0; n < NE; n++) if (n != i1 && acc[n] > v2){ v2 = acc[n]; i2 = n; }
        float v3 = -1e30f;
        #pragma unroll
        for (int n = 0; n < NE; n++) if (n != i1 && n != i2 && acc[n] > v3) v3 = acc[n];

        if (v2 - v3 >= 1e-4f){
            double ex  = exp((double)v2 - (double)v1);
            double inv = 1.0 / (1.0 + ex);
            w1 = (float)inv; w2 = (float)(ex * inv);
        } else {
            // rare: resolve {top2} among near-tie candidates in fp64 (global fp32 x, Wg)
            const float* xr = x + (size_t)tok * DD;
            float thresh = v2 - 1e-3f;
            unsigned cmask = 0u;
            #pragma unroll
            for (int n = 0; n < NE; n++) cmask |= (acc[n] >= thresh) ? (1u << n) : 0u;
            double dv1 = -1.0e300, dv2 = -1.0e300; int di1 = -1, di2 = -1;
            #pragma unroll 1
            for (int n = 0; n < NE; n++){
                if (!((cmask >> n) & 1u)) continue;
                double q0 = 0.0, q1 = 0.0, q2 = 0.0, q3 = 0.0;
                #pragma unroll 4
                for (int d = 0; d < DD; d += 4){
                    q0 = fma((double)xr[d+0], (double)Wg[(size_t)(d+0)*NE + n], q0);
                    q1 = fma((double)xr[d+1], (double)Wg[(size_t)(d+1)*NE + n], q1);
                    q2 = fma((double)xr[d+2], (double)Wg[(size_t)(d+2)*NE + n], q2);
                    q3 = fma((double)xr[d+3], (double)Wg[(size_t)(d+3)*NE + n], q3);
                }
                double sv = (q0 + q1) + (q2 + q3);
                if (sv > dv1){ dv2 = dv1; di2 = di1; dv1 = sv; di1 = n; }
                else if (sv > dv2){ dv2 = sv; di2 = n; }
            }
            i1 = di1; i2 = di2;
            double ex  = exp(dv2 - dv1);
            double inv = 1.0 / (1.0 + ex);
            w1 = (float)inv; w2 = (float)(ex * inv);
        }
        s1 = atomicAdd(&lcnt[i1], 1);
        s2 = atomicAdd(&lcnt[i2], 1);
    }
    __syncthreads();
    if (tid < NE && lcnt[tid] > 0) lbase[tid] = atomicAdd(&counts[tid], lcnt[tid]);
    __syncthreads();
    if (act){
        int tok = t0 + tid;
        int g1 = lbase[i1] + s1;
        int g2 = lbase[i2] + s2;
        bool k1 = g1 < CAP, k2 = g2 < CAP;
        if (k1){ gsl[i1*CAP + g1] = tok;               wts[i1*CAP + g1] = w1; }
        if (k2){ gsl[i2*CAP + g2] = tok | (1 << 20);   wts[i2*CAP + g2] = w2; }
        flags[tok] = (unsigned char)((k1 ? 1 : 0) | (k2 ? 2 : 0));
    }
}

// ---------------- fused expert FFN: BM=64, bf16-x staging, split-destination epilogue ----------------
__global__ __launch_bounds__(512, 4) void k_ffn(
    const unsigned short* __restrict__ xb16,
    const unsigned short* __restrict__ W1f,
    const unsigned short* __restrict__ W2f,
    const float* __restrict__ b1, const float* __restrict__ b2,
    const int* __restrict__ counts,
    const int* __restrict__ gsl, const float* __restrict__ wts,
    float* __restrict__ y, unsigned short* __restrict__ y2h)
{
    __shared__ unsigned char AH[64 * 1024];   // [tok(64)][512 bf16], 16B-chunk XOR swizzle ((tok&7)<<4)

    int p  = blockIdx.x;
    int s  = p >> 3;
    int e  = ((s / NRB) << 3) | (p & 7);
    int rb = s % NRB;

    int cnt = counts[e]; if (cnt > CAP) cnt = CAP;
    int r0 = rb * BM;
    if (r0 >= cnt) return;

    int tid  = threadIdx.x;
    int lane = tid & 63;
    int wv   = tid >> 6;      // 8 waves: wave owns hidden/output cols [wv*64, wv*64+64)
    int lg   = lane >> 4;
    int ll   = lane & 15;

    // ---- stage X from bf16 copy (16B chunks, no conversion) ----
    {
        int row = tid >> 3, seg = tid & 7;
        int gr  = r0 + row;
        char* rowb = (char*)AH + row * 1024;
        int rsw = (row & 7) << 4;
        if (gr < cnt){
            int tk = gsl[e*CAP + gr] & 0xFFFFF;
            const uint4* src = (const uint4*)(xb16 + (size_t)tk*DD + seg*64);
            #pragma unroll
            for (int j = 0; j < 8; j++){
                uint4 v = src[j];
                int chunk = seg*8 + j;
                *(uint4*)(rowb + ((chunk << 4) ^ rsw)) = v;
            }
        } else {
            uint4 zz; zz.x = zz.y = zz.z = zz.w = 0u;
            #pragma unroll
            for (int j = 0; j < 8; j++){
                int chunk = seg*8 + j;
                *(uint4*)(rowb + ((chunk << 4) ^ rsw)) = zz;
            }
        }
    }
    __syncthreads();

    f32x4 acc[4][4];
    #pragma unroll
    for (int a2 = 0; a2 < 4; a2++)
        #pragma unroll
        for (int tt = 0; tt < 4; tt++)
            acc[a2][tt] = (f32x4)0.f;

    // ---- layer 1 (swapped): acc[a][tt] += W1^T-frag(a,c) x X-frag(tt,c) ----
    {
        const unsigned short* Wa = W1f + ((size_t)e << 18) + (size_t)wv*32768;
        bf16x8 f0[4], f1[4];
        #pragma unroll
        for (int a2 = 0; a2 < 4; a2++)
            f0[a2] = *(const bf16x8*)(Wa + a2*8192 + lane*8);
        #pragma unroll 1
        for (int c = 0; c < 16; c += 2){
            #pragma unroll
            for (int a2 = 0; a2 < 4; a2++)
                f1[a2] = *(const bf16x8*)(Wa + a2*8192 + (c+1)*512 + lane*8);
            {
                bf16x8 bx[4];
                #pragma unroll
                for (int tt = 0; tt < 4; tt++){
                    int tok = tt*16 + ll;
                    int bofs = (64*c + 16*lg) ^ ((tok & 7) << 4);
                    bx[tt] = *(const bf16x8*)((char*)AH + tok*1024 + bofs);
                }
                __builtin_amdgcn_s_setprio(1);
                #pragma unroll
                for (int a2 = 0; a2 < 4; a2++)
                    #pragma unroll
                    for (int tt = 0; tt < 4; tt++)
                        acc[a2][tt] = __builtin_amdgcn_mfma_f32_16x16x32_bf16(f0[a2], bx[tt], acc[a2][tt], 0, 0, 0);
                __builtin_amdgcn_s_setprio(0);
            }
            if (c + 2 < 16){
                #pragma unroll
                for (int a2 = 0; a2 < 4; a2++)
                    f0[a2] = *(const bf16x8*)(Wa + a2*8192 + (c+2)*512 + lane*8);
            }
            {
                bf16x8 bx[4];
                #pragma unroll
                for (int tt = 0; tt < 4; tt++){
                    int tok = tt*16 + ll;
                    int bofs = (64*(c+1) + 16*lg) ^ ((tok & 7) << 4);
                    bx[tt] = *(const bf16x8*)((char*)AH + tok*1024 + bofs);
                }
                __builtin_amdgcn_s_setprio(1);
                #pragma unroll
                for (int a2 = 0; a2 < 4; a2++)
                    #pragma unroll
                    for (int tt = 0; tt < 4; tt++)
                        acc[a2][tt] = __builtin_amdgcn_mfma_f32_16x16x32_bf16(f1[a2], bx[tt], acc[a2][tt], 0, 0, 0);
                __builtin_amdgcn_s_setprio(0);
            }
        }
    }
    __syncthreads();

    // ---- h = relu(acc + b1) -> AH as h[tok][n], packed 8B writes ----
    #pragma unroll
    for (int a2 = 0; a2 < 4; a2++){
        int n0 = wv*64 + a2*16 + lg*4;
        float4 bv = *(const float4*)(b1 + e*HH + n0);
        #pragma unroll
        for (int tt = 0; tt < 4; tt++){
            int tok = tt*16 + ll;
            float h0 = acc[a2][tt][0] + bv.x; h0 = h0 > 0.f ? h0 : 0.f;
            float h1 = acc[a2][tt][1] + bv.y; h1 = h1 > 0.f ? h1 : 0.f;
            float h2 = acc[a2][tt][2] + bv.z; h2 = h2 > 0.f ? h2 : 0.f;
            float h3 = acc[a2][tt][3] + bv.w; h3 = h3 > 0.f ? h3 : 0.f;
            uint2 pk;
            pk.x = (unsigned)f2bf(h0) | ((unsigned)f2bf(h1) << 16);
            pk.y = (unsigned)f2bf(h2) | ((unsigned)f2bf(h3) << 16);
            int bofs = (n0*2) ^ ((tok & 7) << 4);
            *(uint2*)((char*)AH + tok*1024 + bofs) = pk;
            acc[a2][tt] = (f32x4)0.f;
        }
    }
    __syncthreads();

    // ---- layer 2: acc[b][tt] += h-frag(tt,kc) @ W2-frag(b,kc) ----
    {
        const unsigned short* Wb = W2f + ((size_t)e << 18) + (size_t)wv*32768;
        bf16x8 f0[4], f1[4];
        #pragma unroll
        for (int b_ = 0; b_ < 4; b_++)
            f0[b_] = *(const bf16x8*)(Wb + b_*8192 + lane*8);
        #pragma unroll 1
        for (int kc = 0; kc < 16; kc += 2){
            #pragma unroll
            for (int b_ = 0; b_ < 4; b_++)
                f1[b_] = *(const bf16x8*)(Wb + b_*8192 + (kc+1)*512 + lane*8);
            {
                bf16x8 ah[4];
                #pragma unroll
                for (int tt = 0; tt < 4; tt++){
                    int tok = tt*16 + ll;
                    int bofs = (64*kc + 16*lg) ^ ((tok & 7) << 4);
                    ah[tt] = *(const bf16x8*)((char*)AH + tok*1024 + bofs);
                }
                __builtin_amdgcn_s_setprio(1);
                #pragma unroll
                for (int b_ = 0; b_ < 4; b_++)
                    #pragma unroll
                    for (int tt = 0; tt < 4; tt++)
                        acc[b_][tt] = __builtin_amdgcn_mfma_f32_16x16x32_bf16(ah[tt], f0[b_], acc[b_][tt], 0, 0, 0);
                __builtin_amdgcn_s_setprio(0);
            }
            if (kc + 2 < 16){
                #pragma unroll
                for (int b_ = 0; b_ < 4; b_++)
                    f0[b_] = *(const bf16x8*)(Wb + b_*8192 + (kc+2)*512 + lane*8);
            }
            {
                bf16x8 ah[4];
                #pragma unroll
                for (int tt = 0; tt < 4; tt++){
                    int tok = tt*16 + ll;
                    int bofs = (64*(kc+1) + 16*lg) ^ ((tok & 7) << 4);
                    ah[tt] = *(const bf16x8*)((char*)AH + tok*1024 + bofs);
                }
                __builtin_amdgcn_s_setprio(1);
                #pragma unroll
                for (int b_ = 0; b_ < 4; b_++)
                    #pragma unroll
                    for (int tt = 0; tt < 4; tt++)
                        acc[b_][tt] = __builtin_amdgcn_mfma_f32_16x16x32_bf16(ah[tt], f1[b_], acc[b_][tt], 0, 0, 0);
                __builtin_amdgcn_s_setprio(0);
            }
        }
    }

    // ---- epilogue: top-1 -> y (fp32 plain), top-2 -> y2h (bf16, weighted) ----
    float bb[4];
    #pragma unroll
    for (int b_ = 0; b_ < 4; b_++)
        bb[b_] = b2[e*DD + wv*64 + b_*16 + ll];

    #pragma unroll
    for (int tt = 0; tt < 4; tt++){
        #pragma unroll
        for (int i = 0; i < 4; i++){
            int rl = tt*16 + lg*4 + i;
            int gr = r0 + rl;
            if (gr < cnt){
                int   v  = gsl[e*CAP + gr];
                int   tk = v & 0xFFFFF;
                float w  = wts[e*CAP + gr];
                if (v >> 20){
                    unsigned short* dst = y2h + (size_t)tk * DD;
                    #pragma unroll
                    for (int b_ = 0; b_ < 4; b_++){
                        int col = wv*64 + b_*16 + ll;
                        dst[col] = f2bf(w * (acc[b_][tt][i] + bb[b_]));
                    }
                } else {
                    float* dst = y + (size_t)tk * DD;
                    #pragma unroll
                    for (int b_ = 0; b_ < 4; b_++){
                        int col = wv*64 + b_*16 + ll;
                        dst[col] = w * (acc[b_][tt][i] + bb[b_]);
                    }
                }
            }
        }
    }
}

// ---------------- combine: y = [k1]y + [k2]bf16(y2), or passthrough x ----------------
__global__ __launch_bounds__(256) void k_comb(
    const float* __restrict__ x, const unsigned short* __restrict__ y2h,
    const unsigned char* __restrict__ flags, float* __restrict__ y)
{
    const float4* x4  = (const float4*)x;
    const uint2*  y24 = (const uint2*)y2h;
    float4* y4 = (float4*)y;
    int nthreads = gridDim.x * 256;
    int g = blockIdx.x * 256 + threadIdx.x;
    #pragma unroll 1
    for (long long idx = g; idx < (long long)BT * 128; idx += nthreads){
        int t = (int)(idx >> 7);
        int f = flags[t];
        if (f == 3){
            float4 a = y4[idx];
            uint2 p = y24[idx];
            a.x += bf2f((unsigned short)(p.x & 0xFFFF));
            a.y += bf2f((unsigned short)(p.x >> 16));
            a.z += bf2f((unsigned short)(p.y & 0xFFFF));
            a.w += bf2f((unsigned short)(p.y >> 16));
            y4[idx] = a;
        } else if (f == 2){
            uint2 p = y24[idx];
            float4 a;
            a.x = bf2f((unsigned short)(p.x & 0xFFFF));
            a.y = bf2f((unsigned short)(p.x >> 16));
            a.z = bf2f((unsigned short)(p.y & 0xFFFF));
            a.w = bf2f((unsigned short)(p.y >> 16));
            y4[idx] = a;
        } else if (f == 0){
            y4[idx] = x4[idx];
        } // f == 1: y already correct
    }
}

extern "C" void kernel_launch(void* const* d_in, const int* in_sizes, int n_in,
                              void* d_out, int out_size, void* d_ws, size_t ws_size,
                              hipStream_t stream)
{
    const float* x  = (const float*)d_in[0];
    const float* Wg = (const float*)d_in[1];
    const float* W1 = (const float*)d_in[2];
    const float* b1 = (const float*)d_in[3];
    const float* W2 = (const float*)d_in[4];
    const float* b2 = (const float*)d_in[5];
    float* y = (float*)d_out;

    char* ws = (char*)d_ws;
    unsigned short* W1f = (unsigned short*)(ws);
    unsigned short* W2f = (unsigned short*)(ws + 16777216);
    size_t b3 = 33554432;
    int*   counts = (int*)  (ws + b3);
    int*   gsl    = (int*)  (ws + b3 + 256);
    float* wts    = (float*)(ws + b3 + 256 + 655360);
    unsigned char* flags = (unsigned char*)(ws + b3 + 256 + 2*655360);
    unsigned short* WgHf = (unsigned short*)(ws + b3 + 256 + 2*655360 + 65536);
    unsigned short* WgLf = (unsigned short*)(ws + b3 + 256 + 2*655360 + 65536 + 32768);
    unsigned short* xb16 = (unsigned short*)(ws + 35651584);                // 67.1 MB
    unsigned short* y2h  = (unsigned short*)(ws + 35651584 + 67108864);     // 67.1 MB

    hipMemsetAsync(counts, 0, 256, stream);
    hipLaunchKernelGGL(k_wgprep, dim3(1), dim3(256), 0, stream, Wg, WgHf, WgLf);
    hipLaunchKernelGGL(k_prep, dim3(2048 + 512), dim3(256), 0, stream,
                       x, Wg, W1, W2, WgHf, WgLf, W1f, W2f, counts, gsl, wts, flags, xb16);
    hipLaunchKernelGGL(k_ffn,  dim3(NE*NRB), dim3(512), 0, stream,
                       xb16, W1f, W2f, b1, b2, counts, gsl, wts, y, y2h);
    hipLaunchKernelGGL(k_comb, dim3(2048), dim3(256), 0, stream, x, y2h, flags, y);
}

// Round 15
// 356.075 us; speedup vs baseline: 1.2466x; 1.1084x over previous
//
#include <hip/hip_runtime.h>
#include <hip/hip_bf16.h>

#define BT 65536
#define DD 512
#define HH 512
#define NE 32
#define CAP 5120
#define BM 64
#define NRB 80   /* CAP/BM */

typedef float  f32x4  __attribute__((ext_vector_type(4)));
typedef short  bf16x8 __attribute__((ext_vector_type(8)));

__device__ __forceinline__ unsigned short f2bf(float f){
    unsigned int u = __builtin_bit_cast(unsigned int, f);
    unsigned int r = (u + 0x7fffu + ((u >> 16) & 1u)) >> 16;
    return (unsigned short)r;
}
__device__ __forceinline__ float bf2f(unsigned short h){
    unsigned int u = ((unsigned int)h) << 16;
    return __builtin_bit_cast(float, u);
}

// ---------------- Wg -> hi/lo MFMA A-fragments (W^T rows = experts) ----------------
// WgHf/WgLf[ef(2)][kc(16)][lane(64)][8]: lane holds Wg[d = kc*32+(lane>>4)*8+j][e = ef*16+(lane&15)]
__global__ __launch_bounds__(256) void k_wgprep(
    const float* __restrict__ Wg,
    unsigned short* __restrict__ WgHf, unsigned short* __restrict__ WgLf)
{
    int entry = blockIdx.x * 256 + threadIdx.x;   // 8 blocks x 256 = 2048 entries
    int ln = entry & 63;
    unsigned short h[8], l[8];
    #pragma unroll
    for (int j = 0; j < 8; j++){
        int d = ((entry >> 6) & 15)*32 + (ln >> 4)*8 + j;
        int e = (entry >> 10)*16 + (ln & 15);
        float v = Wg[d*NE + e];
        unsigned short hi = f2bf(v);
        h[j] = hi;
        l[j] = f2bf(v - bf2f(hi));
    }
    *(bf16x8*)(WgHf + (size_t)entry*8) = *(bf16x8*)h;
    *(bf16x8*)(WgLf + (size_t)entry*8) = *(bf16x8*)l;
}

// ---------------- prep: blocks [0,1024) = register-direct MFMA gate (64 tok); [1024,1536) = weight conv ----------------
__global__ __launch_bounds__(256) void k_prep(
    const float* __restrict__ x, const float* __restrict__ Wg,
    const float* __restrict__ W1, const float* __restrict__ W2,
    const unsigned short* __restrict__ WgHf, const unsigned short* __restrict__ WgLf,
    unsigned short* __restrict__ W1f, unsigned short* __restrict__ W2f,
    int* __restrict__ counts, int* __restrict__ gsl, float* __restrict__ wts,
    unsigned char* __restrict__ flags, unsigned short* __restrict__ xb16)
{
    __shared__ float lg2[64 * 33];            // logits [tok][expert], padded
    __shared__ int lcnt[NE], lbase[NE];

    int tid = threadIdx.x;

    if (blockIdx.x >= 1024){
        // ---------------- weight convert (float4-vectorized, coalesced rows) ----------------
        int b = blockIdx.x - 1024;             // 0..511
        int w = b >> 8;
        int e = (b >> 3) & 31;
        int kq = b & 7;
        const float* src = (w ? W2 : W1) + ((size_t)e << 18);
        unsigned short* dst = (w ? W2f : W1f) + ((size_t)e << 18);
        int n4 = (tid & 127) * 4;
        int kh = tid >> 7;
        #pragma unroll 1
        for (int kg = 0; kg < 4; kg++){
            int k0 = kq*64 + (kg*2 + kh)*8;
            float4 rows[8];
            #pragma unroll
            for (int j = 0; j < 8; j++)
                rows[j] = *(const float4*)&src[(size_t)(k0 + j)*512 + n4];
            unsigned short v0[8], v1[8], v2[8], v3[8];
            #pragma unroll
            for (int j = 0; j < 8; j++){
                v0[j] = f2bf(rows[j].x); v1[j] = f2bf(rows[j].y);
                v2[j] = f2bf(rows[j].z); v3[j] = f2bf(rows[j].w);
            }
            int kc = k0 >> 5, lb = ((k0 >> 3) & 3)*16;
            #pragma unroll
            for (int m = 0; m < 4; m++){
                int n = n4 + m;
                int nt = n >> 4, ln = lb + (n & 15);
                const unsigned short* vv = (m==0)?v0:(m==1)?v1:(m==2)?v2:v3;
                *(bf16x8*)(dst + (((size_t)(nt*16 + kc)*64 + ln) << 3)) = *(const bf16x8*)vv;
            }
        }
        return;
    }

    // ---------------- gate v10: register-direct split-bf16 MFMA, no x LDS tiles ----------------
    int t0 = blockIdx.x * 64;                  // 64 tokens/block, wave wv owns 16
    {
        int lane = tid & 63;
        int wv   = tid >> 6;
        int lg   = lane >> 4, ll = lane & 15;
        int tokl = wv*16 + ll;
        const float* xr = x + (size_t)(t0 + tokl)*DD;

        f32x4 acc0 = (f32x4)0.f, acc1 = (f32x4)0.f;
        #pragma unroll 4
        for (int kc = 0; kc < 16; kc++){
            int d0 = kc*32 + lg*8;
            float4 a = *(const float4*)(xr + d0);
            float4 b = *(const float4*)(xr + d0 + 4);
            unsigned short h[8], l[8];
            h[0]=f2bf(a.x); h[1]=f2bf(a.y); h[2]=f2bf(a.z); h[3]=f2bf(a.w);
            h[4]=f2bf(b.x); h[5]=f2bf(b.y); h[6]=f2bf(b.z); h[7]=f2bf(b.w);
            l[0]=f2bf(a.x-bf2f(h[0])); l[1]=f2bf(a.y-bf2f(h[1]));
            l[2]=f2bf(a.z-bf2f(h[2])); l[3]=f2bf(a.w-bf2f(h[3]));
            l[4]=f2bf(b.x-bf2f(h[4])); l[5]=f2bf(b.y-bf2f(h[5]));
            l[6]=f2bf(b.z-bf2f(h[6])); l[7]=f2bf(b.w-bf2f(h[7]));
            bf16x8 bh = *(bf16x8*)h, bl = *(bf16x8*)l;
            *(bf16x8*)(xb16 + (size_t)(t0 + tokl)*DD + d0) = bh;   // byproduct for ffn
            bf16x8 ah0 = *(const bf16x8*)(WgHf + ((size_t)(kc*64 + lane) << 3));
            bf16x8 al0 = *(const bf16x8*)(WgLf + ((size_t)(kc*64 + lane) << 3));
            bf16x8 ah1 = *(const bf16x8*)(WgHf + ((size_t)(1024 + kc*64 + lane) << 3));
            bf16x8 al1 = *(const bf16x8*)(WgLf + ((size_t)(1024 + kc*64 + lane) << 3));
            acc0 = __builtin_amdgcn_mfma_f32_16x16x32_bf16(ah0, bh, acc0, 0, 0, 0);
            acc0 = __builtin_amdgcn_mfma_f32_16x16x32_bf16(ah0, bl, acc0, 0, 0, 0);
            acc0 = __builtin_amdgcn_mfma_f32_16x16x32_bf16(al0, bh, acc0, 0, 0, 0);
            acc1 = __builtin_amdgcn_mfma_f32_16x16x32_bf16(ah1, bh, acc1, 0, 0, 0);
            acc1 = __builtin_amdgcn_mfma_f32_16x16x32_bf16(ah1, bl, acc1, 0, 0, 0);
            acc1 = __builtin_amdgcn_mfma_f32_16x16x32_bf16(al1, bh, acc1, 0, 0, 0);
        }
        #pragma unroll
        for (int i = 0; i < 4; i++){
            lg2[tokl*33 +      lg*4 + i] = acc0[i];
            lg2[tokl*33 + 16 + lg*4 + i] = acc1[i];
        }
    }
    if (tid < NE) lcnt[tid] = 0;
    __syncthreads();

    // selection: one thread per token; barriers in UNIFORM control flow
    float w1 = 0.f, w2 = 0.f;
    int i1 = 0, i2 = 0, s1 = 0, s2 = 0;
    bool act = (tid < 64);
    if (act){
        int tok = t0 + tid;
        float acc[NE];
        #pragma unroll
        for (int n = 0; n < NE; n++) acc[n] = lg2[tid*33 + n];

        float v1 = -1e30f; i1 = -1;
        #pragma unroll
        for (int n = 0; n < NE; n++) if (acc[n] > v1){ v1 = acc[n]; i1 = n; }
        float v2 = -1e30f; i2 = -1;
        #pragma unroll
        for (int n = 0; n < NE; n++) if (n != i1 && acc[n] > v2){ v2 = acc[n]; i2 = n; }
        float v3 = -1e30f;
        #pragma unroll
        for (int n = 0; n < NE; n++) if (n != i1 && n != i2 && acc[n] > v3) v3 = acc[n];

        if (v2 - v3 >= 1e-4f){
            double ex  = exp((double)v2 - (double)v1);
            double inv = 1.0 / (1.0 + ex);
            w1 = (float)inv; w2 = (float)(ex * inv);
        } else {
            // rare: resolve {top2} among near-tie candidates in fp64 (global fp32 x, Wg)
            const float* xr = x + (size_t)tok * DD;
            float thresh = v2 - 1e-3f;
            unsigned cmask = 0u;
            #pragma unroll
            for (int n = 0; n < NE; n++) cmask |= (acc[n] >= thresh) ? (1u << n) : 0u;
            double dv1 = -1.0e300, dv2 = -1.0e300; int di1 = -1, di2 = -1;
            #pragma unroll 1
            for (int n = 0; n < NE; n++){
                if (!((cmask >> n) & 1u)) continue;
                double q0 = 0.0, q1 = 0.0, q2 = 0.0, q3 = 0.0;
                #pragma unroll 4
                for (int d = 0; d < DD; d += 4){
                    q0 = fma((double)xr[d+0], (double)Wg[(size_t)(d+0)*NE + n], q0);
                    q1 = fma((double)xr[d+1], (double)Wg[(size_t)(d+1)*NE + n], q1);
                    q2 = fma((double)xr[d+2], (double)Wg[(size_t)(d+2)*NE + n], q2);
                    q3 = fma((double)xr[d+3], (double)Wg[(size_t)(d+3)*NE + n], q3);
                }
                double sv = (q0 + q1) + (q2 + q3);
                if (sv > dv1){ dv2 = dv1; di2 = di1; dv1 = sv; di1 = n; }
                else if (sv > dv2){ dv2 = sv; di2 = n; }
            }
            i1 = di1; i2 = di2;
            double ex  = exp(dv2 - dv1);
            double inv = 1.0 / (1.0 + ex);
            w1 = (float)inv; w2 = (float)(ex * inv);
        }
        s1 = atomicAdd(&lcnt[i1], 1);
        s2 = atomicAdd(&lcnt[i2], 1);
    }
    __syncthreads();
    if (tid < NE && lcnt[tid] > 0) lbase[tid] = atomicAdd(&counts[tid], lcnt[tid]);
    __syncthreads();
    if (act){
        int tok = t0 + tid;
        int g1 = lbase[i1] + s1;
        int g2 = lbase[i2] + s2;
        bool k1 = g1 < CAP, k2 = g2 < CAP;
        if (k1){ gsl[i1*CAP + g1] = tok;               wts[i1*CAP + g1] = w1; }
        if (k2){ gsl[i2*CAP + g2] = tok | (1 << 20);   wts[i2*CAP + g2] = w2; }
        flags[tok] = (unsigned char)((k1 ? 1 : 0) | (k2 ? 2 : 0));
    }
}

// ---------------- fused expert FFN: BM=64, bf16-x staging, split-destination epilogue ----------------
__global__ __launch_bounds__(512, 4) void k_ffn(
    const unsigned short* __restrict__ xb16,
    const unsigned short* __restrict__ W1f,
    const unsigned short* __restrict__ W2f,
    const float* __restrict__ b1, const float* __restrict__ b2,
    const int* __restrict__ counts,
    const int* __restrict__ gsl, const float* __restrict__ wts,
    float* __restrict__ y, unsigned short* __restrict__ y2h)
{
    __shared__ unsigned char AH[64 * 1024];   // [tok(64)][512 bf16], 16B-chunk XOR swizzle ((tok&7)<<4)

    int p  = blockIdx.x;
    int s  = p >> 3;
    int e  = ((s / NRB) << 3) | (p & 7);
    int rb = s % NRB;

    int cnt = counts[e]; if (cnt > CAP) cnt = CAP;
    int r0 = rb * BM;
    if (r0 >= cnt) return;

    int tid  = threadIdx.x;
    int lane = tid & 63;
    int wv   = tid >> 6;      // 8 waves: wave owns hidden/output cols [wv*64, wv*64+64)
    int lg   = lane >> 4;
    int ll   = lane & 15;

    // ---- stage X from bf16 copy (16B chunks, no conversion) ----
    {
        int row = tid >> 3, seg = tid & 7;
        int gr  = r0 + row;
        char* rowb = (char*)AH + row * 1024;
        int rsw = (row & 7) << 4;
        if (gr < cnt){
            int tk = gsl[e*CAP + gr] & 0xFFFFF;
            const uint4* src = (const uint4*)(xb16 + (size_t)tk*DD + seg*64);
            #pragma unroll
            for (int j = 0; j < 8; j++){
                uint4 v = src[j];
                int chunk = seg*8 + j;
                *(uint4*)(rowb + ((chunk << 4) ^ rsw)) = v;
            }
        } else {
            uint4 zz; zz.x = zz.y = zz.z = zz.w = 0u;
            #pragma unroll
            for (int j = 0; j < 8; j++){
                int chunk = seg*8 + j;
                *(uint4*)(rowb + ((chunk << 4) ^ rsw)) = zz;
            }
        }
    }
    __syncthreads();

    f32x4 acc[4][4];
    #pragma unroll
    for (int a2 = 0; a2 < 4; a2++)
        #pragma unroll
        for (int tt = 0; tt < 4; tt++)
            acc[a2][tt] = (f32x4)0.f;

    // ---- layer 1 (swapped): acc[a][tt] += W1^T-frag(a,c) x X-frag(tt,c) ----
    {
        const unsigned short* Wa = W1f + ((size_t)e << 18) + (size_t)wv*32768;
        bf16x8 f0[4], f1[4];
        #pragma unroll
        for (int a2 = 0; a2 < 4; a2++)
            f0[a2] = *(const bf16x8*)(Wa + a2*8192 + lane*8);
        #pragma unroll 1
        for (int c = 0; c < 16; c += 2){
            #pragma unroll
            for (int a2 = 0; a2 < 4; a2++)
                f1[a2] = *(const bf16x8*)(Wa + a2*8192 + (c+1)*512 + lane*8);
            {
                bf16x8 bx[4];
                #pragma unroll
                for (int tt = 0; tt < 4; tt++){
                    int tok = tt*16 + ll;
                    int bofs = (64*c + 16*lg) ^ ((tok & 7) << 4);
                    bx[tt] = *(const bf16x8*)((char*)AH + tok*1024 + bofs);
                }
                __builtin_amdgcn_s_setprio(1);
                #pragma unroll
                for (int a2 = 0; a2 < 4; a2++)
                    #pragma unroll
                    for (int tt = 0; tt < 4; tt++)
                        acc[a2][tt] = __builtin_amdgcn_mfma_f32_16x16x32_bf16(f0[a2], bx[tt], acc[a2][tt], 0, 0, 0);
                __builtin_amdgcn_s_setprio(0);
            }
            if (c + 2 < 16){
                #pragma unroll
                for (int a2 = 0; a2 < 4; a2++)
                    f0[a2] = *(const bf16x8*)(Wa + a2*8192 + (c+2)*512 + lane*8);
            }
            {
                bf16x8 bx[4];
                #pragma unroll
                for (int tt = 0; tt < 4; tt++){
                    int tok = tt*16 + ll;
                    int bofs = (64*(c+1) + 16*lg) ^ ((tok & 7) << 4);
                    bx[tt] = *(const bf16x8*)((char*)AH + tok*1024 + bofs);
                }
                __builtin_amdgcn_s_setprio(1);
                #pragma unroll
                for (int a2 = 0; a2 < 4; a2++)
                    #pragma unroll
                    for (int tt = 0; tt < 4; tt++)
                        acc[a2][tt] = __builtin_amdgcn_mfma_f32_16x16x32_bf16(f1[a2], bx[tt], acc[a2][tt], 0, 0, 0);
                __builtin_amdgcn_s_setprio(0);
            }
        }
    }
    __syncthreads();

    // ---- h = relu(acc + b1) -> AH as h[tok][n], packed 8B writes ----
    #pragma unroll
    for (int a2 = 0; a2 < 4; a2++){
        int n0 = wv*64 + a2*16 + lg*4;
        float4 bv = *(const float4*)(b1 + e*HH + n0);
        #pragma unroll
        for (int tt = 0; tt < 4; tt++){
            int tok = tt*16 + ll;
            float h0 = acc[a2][tt][0] + bv.x; h0 = h0 > 0.f ? h0 : 0.f;
            float h1 = acc[a2][tt][1] + bv.y; h1 = h1 > 0.f ? h1 : 0.f;
            float h2 = acc[a2][tt][2] + bv.z; h2 = h2 > 0.f ? h2 : 0.f;
            float h3 = acc[a2][tt][3] + bv.w; h3 = h3 > 0.f ? h3 : 0.f;
            uint2 pk;
            pk.x = (unsigned)f2bf(h0) | ((unsigned)f2bf(h1) << 16);
            pk.y = (unsigned)f2bf(h2) | ((unsigned)f2bf(h3) << 16);
            int bofs = (n0*2) ^ ((tok & 7) << 4);
            *(uint2*)((char*)AH + tok*1024 + bofs) = pk;
            acc[a2][tt] = (f32x4)0.f;
        }
    }
    __syncthreads();

    // ---- layer 2: acc[b][tt] += h-frag(tt,kc) @ W2-frag(b,kc) ----
    {
        const unsigned short* Wb = W2f + ((size_t)e << 18) + (size_t)wv*32768;
        bf16x8 f0[4], f1[4];
        #pragma unroll
        for (int b_ = 0; b_ < 4; b_++)
            f0[b_] = *(const bf16x8*)(Wb + b_*8192 + lane*8);
        #pragma unroll 1
        for (int kc = 0; kc < 16; kc += 2){
            #pragma unroll
            for (int b_ = 0; b_ < 4; b_++)
                f1[b_] = *(const bf16x8*)(Wb + b_*8192 + (kc+1)*512 + lane*8);
            {
                bf16x8 ah[4];
                #pragma unroll
                for (int tt = 0; tt < 4; tt++){
                    int tok = tt*16 + ll;
                    int bofs = (64*kc + 16*lg) ^ ((tok & 7) << 4);
                    ah[tt] = *(const bf16x8*)((char*)AH + tok*1024 + bofs);
                }
                __builtin_amdgcn_s_setprio(1);
                #pragma unroll
                for (int b_ = 0; b_ < 4; b_++)
                    #pragma unroll
                    for (int tt = 0; tt < 4; tt++)
                        acc[b_][tt] = __builtin_amdgcn_mfma_f32_16x16x32_bf16(ah[tt], f0[b_], acc[b_][tt], 0, 0, 0);
                __builtin_amdgcn_s_setprio(0);
            }
            if (kc + 2 < 16){
                #pragma unroll
                for (int b_ = 0; b_ < 4; b_++)
                    f0[b_] = *(const bf16x8*)(Wb + b_*8192 + (kc+2)*512 + lane*8);
            }
            {
                bf16x8 ah[4];
                #pragma unroll
                for (int tt = 0; tt < 4; tt++){
                    int tok = tt*16 + ll;
                    int bofs = (64*(kc+1) + 16*lg) ^ ((tok & 7) << 4);
                    ah[tt] = *(const bf16x8*)((char*)AH + tok*1024 + bofs);
                }
                __builtin_amdgcn_s_setprio(1);
                #pragma unroll
                for (int b_ = 0; b_ < 4; b_++)
                    #pragma unroll
                    for (int tt = 0; tt < 4; tt++)
                        acc[b_][tt] = __builtin_amdgcn_mfma_f32_16x16x32_bf16(ah[tt], f1[b_], acc[b_][tt], 0, 0, 0);
                __builtin_amdgcn_s_setprio(0);
            }
        }
    }

    // ---- epilogue: top-1 -> y (fp32 plain), top-2 -> y2h (bf16, weighted) ----
    float bb[4];
    #pragma unroll
    for (int b_ = 0; b_ < 4; b_++)
        bb[b_] = b2[e*DD + wv*64 + b_*16 + ll];

    #pragma unroll
    for (int tt = 0; tt < 4; tt++){
        #pragma unroll
        for (int i = 0; i < 4; i++){
            int rl = tt*16 + lg*4 + i;
            int gr = r0 + rl;
            if (gr < cnt){
                int   v  = gsl[e*CAP + gr];
                int   tk = v & 0xFFFFF;
                float w  = wts[e*CAP + gr];
                if (v >> 20){
                    unsigned short* dst = y2h + (size_t)tk * DD;
                    #pragma unroll
                    for (int b_ = 0; b_ < 4; b_++){
                        int col = wv*64 + b_*16 + ll;
                        dst[col] = f2bf(w * (acc[b_][tt][i] + bb[b_]));
                    }
                } else {
                    float* dst = y + (size_t)tk * DD;
                    #pragma unroll
                    for (int b_ = 0; b_ < 4; b_++){
                        int col = wv*64 + b_*16 + ll;
                        dst[col] = w * (acc[b_][tt][i] + bb[b_]);
                    }
                }
            }
        }
    }
}

// ---------------- combine: y = [k1]y + [k2]bf16(y2), or passthrough x ----------------
__global__ __launch_bounds__(256) void k_comb(
    const float* __restrict__ x, const unsigned short* __restrict__ y2h,
    const unsigned char* __restrict__ flags, float* __restrict__ y)
{
    const float4* x4  = (const float4*)x;
    const uint2*  y24 = (const uint2*)y2h;
    float4* y4 = (float4*)y;
    int nthreads = gridDim.x * 256;
    int g = blockIdx.x * 256 + threadIdx.x;
    #pragma unroll 1
    for (long long idx = g; idx < (long long)BT * 128; idx += nthreads){
        int t = (int)(idx >> 7);
        int f = flags[t];
        if (f == 3){
            float4 a = y4[idx];
            uint2 p = y24[idx];
            a.x += bf2f((unsigned short)(p.x & 0xFFFF));
            a.y += bf2f((unsigned short)(p.x >> 16));
            a.z += bf2f((unsigned short)(p.y & 0xFFFF));
            a.w += bf2f((unsigned short)(p.y >> 16));
            y4[idx] = a;
        } else if (f == 2){
            uint2 p = y24[idx];
            float4 a;
            a.x = bf2f((unsigned short)(p.x & 0xFFFF));
            a.y = bf2f((unsigned short)(p.x >> 16));
            a.z = bf2f((unsigned short)(p.y & 0xFFFF));
            a.w = bf2f((unsigned short)(p.y >> 16));
            y4[idx] = a;
        } else if (f == 0){
            y4[idx] = x4[idx];
        } // f == 1: y already correct
    }
}

extern "C" void kernel_launch(void* const* d_in, const int* in_sizes, int n_in,
                              void* d_out, int out_size, void* d_ws, size_t ws_size,
                              hipStream_t stream)
{
    const float* x  = (const float*)d_in[0];
    const float* Wg = (const float*)d_in[1];
    const float* W1 = (const float*)d_in[2];
    const float* b1 = (const float*)d_in[3];
    const float* W2 = (const float*)d_in[4];
    const float* b2 = (const float*)d_in[5];
    float* y = (float*)d_out;

    char* ws = (char*)d_ws;
    unsigned short* W1f = (unsigned short*)(ws);
    unsigned short* W2f = (unsigned short*)(ws + 16777216);
    size_t b3 = 33554432;
    int*   counts = (int*)  (ws + b3);
    int*   gsl    = (int*)  (ws + b3 + 256);
    float* wts    = (float*)(ws + b3 + 256 + 655360);
    unsigned char* flags = (unsigned char*)(ws + b3 + 256 + 2*655360);
    unsigned short* WgHf = (unsigned short*)(ws + b3 + 256 + 2*655360 + 65536);
    unsigned short* WgLf = (unsigned short*)(ws + b3 + 256 + 2*655360 + 65536 + 32768);
    unsigned short* xb16 = (unsigned short*)(ws + 35651584);                // 67.1 MB
    unsigned short* y2h  = (unsigned short*)(ws + 35651584 + 67108864);     // 67.1 MB

    hipMemsetAsync(counts, 0, 256, stream);
    hipLaunchKernelGGL(k_wgprep, dim3(8), dim3(256), 0, stream, Wg, WgHf, WgLf);
    hipLaunchKernelGGL(k_prep, dim3(1024 + 512), dim3(256), 0, stream,
                       x, Wg, W1, W2, WgHf, WgLf, W1f, W2f, counts, gsl, wts, flags, xb16);
    hipLaunchKernelGGL(k_ffn,  dim3(NE*NRB), dim3(512), 0, stream,
                       xb16, W1f, W2f, b1, b2, counts, gsl, wts, y, y2h);
    hipLaunchKernelGGL(k_comb, dim3(2048), dim3(256), 0, stream, x, y2h, flags, y);
}